// Round 4
// baseline (2661.630 us; speedup 1.0000x reference)
//
#include <hip/hip_runtime.h>

// ---------------------------------------------------------------------------
// SelfMatchEncoder: additive self-attention + bidirectional GRU
// N=1000, B=8, D=256, H=128
// ---------------------------------------------------------------------------

#define N_ 1000
#define B_ 8
#define D_ 256
#define H_ 128
#define G3_ 384  // 3*H
#define KTANH 2.8853900817779268f  // 2*log2(e)

typedef __attribute__((ext_vector_type(8))) short short8_t;
typedef __attribute__((ext_vector_type(4))) short short4_t;
typedef __attribute__((ext_vector_type(4))) float f32x4;

__device__ __forceinline__ float tanh_fast(float x) {
  float e = __expf(2.f * x);
  return 1.f - 2.f / (e + 1.f);
}
__device__ __forceinline__ float sigmoid_fast(float x) {
  return 1.f / (1.f + __expf(-x));
}
__device__ __forceinline__ unsigned short f2bf(float f) {
  unsigned u = __float_as_uint(f);
  unsigned r = u + 0x7fffu + ((u >> 16) & 1u);
  return (unsigned short)(r >> 16);
}
__device__ __forceinline__ float bf2f(unsigned short b) {
  return __uint_as_float(((unsigned)b) << 16);
}

// ---------------------------------------------------------------------------
// K1: vp[n,b,h] = (sum_d pin[n,b,d]*W0[h,d]) * KTANH  (pre-scaled for exp2)
// ---------------------------------------------------------------------------
__global__ void k_vp(const float* __restrict__ pin, const float* __restrict__ W0,
                     float* __restrict__ vpR, float* __restrict__ vpT) {
  int n = blockIdx.x;
  int tid = threadIdx.x;  // 256
  __shared__ float xs[B_][D_];
  for (int k = 0; k < 8; ++k) {
    int idx = k * 256 + tid;  // 2048
    xs[idx >> 8][idx & 255] = pin[(size_t)n * (B_ * D_) + idx];
  }
  __syncthreads();
  for (int k = 0; k < 4; ++k) {
    int o = k * 256 + tid;  // 1024 = 8b * 128h
    int b = o >> 7, h = o & 127;
    const float4* wr = (const float4*)(W0 + (size_t)h * D_);
    float acc = 0.f;
#pragma unroll 8
    for (int dq = 0; dq < 64; ++dq) {
      float4 w = wr[dq];
      acc += xs[b][dq * 4 + 0] * w.x + xs[b][dq * 4 + 1] * w.y +
             xs[b][dq * 4 + 2] * w.z + xs[b][dq * 4 + 3] * w.w;
    }
    acc *= KTANH;
    vpR[((size_t)b * N_ + n) * H_ + h] = acc;
    vpT[((size_t)b * H_ + h) * N_ + n] = acc;
  }
}

// ---------------------------------------------------------------------------
// K2: S[b,i,j] = VsSum - 2*sum_h vs[h]/(exp2(vp_i+vp_j)+1)  (vp pre-scaled)
// ---------------------------------------------------------------------------
__global__ void k_scores(const float* __restrict__ vpR, const float* __restrict__ vpT,
                         const float* __restrict__ vs, const int* __restrict__ mask,
                         float* __restrict__ S) {
  int b = blockIdx.y;
  int i0 = blockIdx.x * 8;
  int tid = threadIdx.x;  // 256
  __shared__ float vpi[8][H_];
  __shared__ float vss[H_];
  __shared__ float vpj[32][256];
  for (int k = 0; k < 4; ++k) {
    int o = k * 256 + tid;  // 1024
    vpi[o >> 7][o & 127] = vpR[((size_t)b * N_ + i0 + (o >> 7)) * H_ + (o & 127)];
  }
  if (tid < H_) vss[tid] = vs[tid];
  __syncthreads();
  float VsSum = 0.f;
  for (int h = 0; h < H_; ++h) VsSum += vss[h];

  for (int jt = 0; jt < 4; ++jt) {
    int j0 = jt * 256;
    int cnt = min(256, N_ - j0);
    float acc[8] = {0.f, 0.f, 0.f, 0.f, 0.f, 0.f, 0.f, 0.f};
    for (int hc = 0; hc < 4; ++hc) {
      __syncthreads();
      for (int hh = 0; hh < 32; ++hh)
        vpj[hh][tid] = (tid < cnt) ? vpT[((size_t)b * H_ + hc * 32 + hh) * N_ + j0 + tid] : 0.f;
      __syncthreads();
      if (tid < cnt) {
        for (int hh = 0; hh < 32; ++hh) {
          float vj = vpj[hh][tid];
          float vsh = vss[hc * 32 + hh];
#pragma unroll
          for (int i = 0; i < 8; ++i) {
            float e = exp2f(vpi[i][hc * 32 + hh] + vj);
            float r = __builtin_amdgcn_rcpf(e + 1.f);
            acc[i] = fmaf(vsh, r, acc[i]);
          }
        }
      }
    }
    if (tid < cnt) {
      int mj = mask[(size_t)(j0 + tid) * B_ + b];
#pragma unroll
      for (int i = 0; i < 8; ++i)
        S[((size_t)b * N_ + i0 + i) * N_ + j0 + tid] = mj ? -1e30f : (VsSum - 2.f * acc[i]);
    }
  }
}

// ---------------------------------------------------------------------------
// K3: per-row softmax stats (max, 1/sumexp)
// ---------------------------------------------------------------------------
__global__ void k_rowstats(const float* __restrict__ S, float* __restrict__ m_,
                           float* __restrict__ rl_) {
  int i = blockIdx.x, b = blockIdx.y;
  int lane = threadIdx.x;  // 64
  const float* row = S + ((size_t)b * N_ + i) * N_;
  float mx = -3.0e38f;
  for (int j = lane; j < N_; j += 64) mx = fmaxf(mx, row[j]);
  for (int off = 32; off; off >>= 1) mx = fmaxf(mx, __shfl_xor(mx, off));
  float s = 0.f;
  for (int j = lane; j < N_; j += 64) s += __expf(row[j] - mx);
  for (int off = 32; off; off >>= 1) s += __shfl_xor(s, off);
  if (lane == 0) {
    m_[b * N_ + i] = mx;
    rl_[b * N_ + i] = 1.f / s;
  }
}

// ---------------------------------------------------------------------------
// K4: att[i,b,:] = sum_j P[i,j]*pin[j,b,:]; writes rnn_in = [att | pin]
// 16 i-rows x 256 d per block; thread = (iq=tid>>6 -> 4 i's, dg=tid&63 -> 4 d's)
// ---------------------------------------------------------------------------
__global__ void k_pv(const float* __restrict__ S, const float* __restrict__ m_,
                     const float* __restrict__ rl_, const float* __restrict__ pin,
                     float* __restrict__ rnn) {
  int b = blockIdx.y;
  int i0 = blockIdx.x * 16;
  int tid = threadIdx.x;  // 256
  int dg = tid & 63, iq = tid >> 6;
  __shared__ float ps[32][D_];
  __shared__ float PsT[32][16];
  __shared__ float mi[16], ri[16];
  if (tid < 16) {
    int ii = i0 + tid;
    mi[tid] = (ii < N_) ? m_[b * N_ + ii] : 0.f;
    ri[tid] = (ii < N_) ? rl_[b * N_ + ii] : 0.f;
  }
  f32x4 acc[4];
#pragma unroll
  for (int ii = 0; ii < 4; ++ii) acc[ii] = (f32x4){0.f, 0.f, 0.f, 0.f};

  for (int jc = 0; jc < 32; ++jc) {  // 1000 = 31*32 + 8
    int j0 = jc * 32;
    int cj = min(32, N_ - j0);
    __syncthreads();
    // stage V rows (each of 4 waves loads rows iq, iq+4, ... jj = rr*4+iq)
#pragma unroll
    for (int rr = 0; rr < 8; ++rr) {
      int jj = rr * 4 + iq;
      if (jj < cj)
        *(f32x4*)&ps[jj][dg * 4] =
            *(const f32x4*)&pin[((size_t)(j0 + jj) * B_ + b) * D_ + dg * 4];
    }
    // P transposed tile
#pragma unroll
    for (int k = 0; k < 2; ++k) {
      int v = k * 256 + tid;  // 512 = 32j * 16i
      int jj = v >> 4, il = v & 15;
      float p = 0.f;
      if (jj < cj && i0 + il < N_)
        p = __expf(S[((size_t)b * N_ + i0 + il) * N_ + j0 + jj] - mi[il]) * ri[il];
      PsT[jj][il] = p;
    }
    __syncthreads();
    for (int jj = 0; jj < 32; ++jj) {
      f32x4 pv = *(f32x4*)&ps[jj][dg * 4];
      f32x4 p4 = *(f32x4*)&PsT[jj][iq * 4];  // wave-uniform broadcast
#pragma unroll
      for (int ii = 0; ii < 4; ++ii) acc[ii] += pv * p4[ii];
    }
  }
#pragma unroll
  for (int ii = 0; ii < 4; ++ii) {
    int i = i0 + iq * 4 + ii;
    if (i < N_) {
      size_t base = ((size_t)i * B_ + b) * (2 * D_);
      *(f32x4*)&rnn[base + dg * 4] = acc[ii];
      *(f32x4*)&rnn[base + D_ + dg * 4] =
          *(const f32x4*)&pin[((size_t)i * B_ + b) * D_ + dg * 4];
    }
  }
}

// ---------------------------------------------------------------------------
// K5: xw[n,b,g] = bias[g] + sum_k rnn[n,b,k]*W_ih[g,k]   (both directions)
// ---------------------------------------------------------------------------
__global__ void k_xw(const float* __restrict__ rnn, const float* __restrict__ Wf,
                     const float* __restrict__ bf, const float* __restrict__ Wb,
                     const float* __restrict__ bb, float* __restrict__ xwf,
                     float* __restrict__ xwb) {
  int n = blockIdx.x;
  int dir = blockIdx.y;
  const float* W = dir ? Wb : Wf;
  const float* bias = dir ? bb : bf;
  float* xw = dir ? xwb : xwf;
  int tid = threadIdx.x;  // 256
  __shared__ float xs[B_][2 * D_];
  for (int k = 0; k < 16; ++k) {
    int o = k * 256 + tid;  // 4096
    xs[o >> 9][o & 511] = rnn[(size_t)n * (B_ * 2 * D_) + o];
  }
  __syncthreads();
  for (int gk = 0; gk < 2; ++gk) {
    int g = gk * 256 + tid;
    if (g < G3_) {
      float acc[8];
      float bv = bias[g];
#pragma unroll
      for (int b = 0; b < 8; ++b) acc[b] = bv;
      const float4* wr = (const float4*)(W + (size_t)g * (2 * D_));
      for (int kq = 0; kq < 128; ++kq) {
        float4 w = wr[kq];
#pragma unroll
        for (int b = 0; b < 8; ++b) {
          float4 x = *(const float4*)&xs[b][kq * 4];
          acc[b] += x.x * w.x + x.y * w.y + x.z * w.z + x.w * w.w;
        }
      }
#pragma unroll
      for (int b = 0; b < 8; ++b)
        xw[((size_t)n * B_ + b) * G3_ + g] = acc[b];
    }
  }
}

// ---------------------------------------------------------------------------
// K6: GRU scan v2. 2 blocks (dir) x 256 threads (4 waves).
// - MFMA operands swapped: A = W_hh tile (16 g), B = h^T (b cols) so each
//   lane's C-frag holds 4 consecutive g for one b -> gates fully in-register.
// - h (hi/lo bf16 split) stored in LDS in MFMA-fragment order:
//   frag[kc][slot=l][j]: conflict-free ds_read_b128 (slot l = (krow<<4)|b).
// - double-buffered frags -> ONE barrier per step.
// - hi/lo split (3 MFMA terms) keeps fp32-level accuracy over 1000 steps.
// ---------------------------------------------------------------------------
__global__ __launch_bounds__(256) void k_gru(const float* __restrict__ xwf,
                                             const float* __restrict__ xwb,
                                             const float* __restrict__ Whf,
                                             const float* __restrict__ Whb,
                                             const float* __restrict__ bhf,
                                             const float* __restrict__ bhb,
                                             float* __restrict__ out) {
  int dir = blockIdx.x;
  const float* xw = dir ? xwb : xwf;
  const float* Wh = dir ? Whb : Whf;
  const float* bh = dir ? bhb : bhf;

  __shared__ short hfhi[2][4][64][8];  // buf, kc, slot, j  (4KB each buf)
  __shared__ short hflo[2][4][64][8];

  int tid = threadIdx.x;
  int w = tid >> 6;     // wave 0..3, owns g-blocks 2w, 2w+1 per gate
  int lane = tid & 63;
  int col = lane & 15;  // b index (0..7 valid) for B-frag and C cols
  int krow = lane >> 4; // k-slice selector; C rows = krow*4+i

  for (int k = tid; k < 2 * 4 * 64 * 8; k += 256) {
    ((short*)hfhi)[k] = 0;
    ((short*)hflo)[k] = 0;
  }

  // W fragments (A operand): lane holds Wh[g0+col][kc*32+krow*8+j]
  short8_t whi[3][2][4], wlo[3][2][4];
  f32x4 bhv[3][2];
#pragma unroll
  for (int gate = 0; gate < 3; ++gate) {
#pragma unroll
    for (int gb = 0; gb < 2; ++gb) {
      int g0 = gate * 128 + (w * 2 + gb) * 16;
      bhv[gate][gb] = *(const f32x4*)&bh[g0 + krow * 4];
#pragma unroll
      for (int kc = 0; kc < 4; ++kc) {
        const float* wp = Wh + (size_t)(g0 + col) * H_ + kc * 32 + krow * 8;
        short8_t hi8, lo8;
#pragma unroll
        for (int j = 0; j < 8; ++j) {
          float v = wp[j];
          unsigned short h = f2bf(v);
          hi8[j] = (short)h;
          lo8[j] = (short)f2bf(v - bf2f(h));
        }
        whi[gate][gb][kc] = hi8;
        wlo[gate][gb][kc] = lo8;
      }
    }
  }
  float hprev[2][4] = {{0.f, 0.f, 0.f, 0.f}, {0.f, 0.f, 0.f, 0.f}};
  __syncthreads();

  int buf = 0;
  for (int t = 0; t < N_; ++t) {
    int n = dir ? (N_ - 1 - t) : t;

    // h fragments (B operand): conflict-free contiguous b128 reads
    short8_t fhi[4], flo[4];
#pragma unroll
    for (int kc = 0; kc < 4; ++kc) {
      fhi[kc] = *(const short8_t*)&hfhi[buf][kc][lane][0];
      flo[kc] = *(const short8_t*)&hflo[buf][kc][lane][0];
    }

    // xw for this step (consumed after MFMA -> latency hidden)
    f32x4 xg[3][2];
    if (col < 8) {
#pragma unroll
      for (int gate = 0; gate < 3; ++gate)
#pragma unroll
        for (int gb = 0; gb < 2; ++gb)
          xg[gate][gb] = *(const f32x4*)&xw[((size_t)n * B_ + col) * G3_ +
                                            gate * 128 + (w * 2 + gb) * 16 + krow * 4];
    }

    // hw = h @ W^T via swapped-operand MFMA (3-term hi/lo split)
    f32x4 acc[3][2];
#pragma unroll
    for (int gate = 0; gate < 3; ++gate) {
#pragma unroll
      for (int gb = 0; gb < 2; ++gb) {
        f32x4 a = {0.f, 0.f, 0.f, 0.f};
#pragma unroll
        for (int kc = 0; kc < 4; ++kc) {
          a = __builtin_amdgcn_mfma_f32_16x16x32_bf16(whi[gate][gb][kc], fhi[kc], a, 0, 0, 0);
          a = __builtin_amdgcn_mfma_f32_16x16x32_bf16(wlo[gate][gb][kc], fhi[kc], a, 0, 0, 0);
          a = __builtin_amdgcn_mfma_f32_16x16x32_bf16(whi[gate][gb][kc], flo[kc], a, 0, 0, 0);
        }
        acc[gate][gb] = a;
      }
    }

    // gates entirely in registers; write h2 to next frag buffer
    if (col < 8) {
#pragma unroll
      for (int gb = 0; gb < 2; ++gb) {
        f32x4 h2v;
#pragma unroll
        for (int i = 0; i < 4; ++i) {
          float r = sigmoid_fast(xg[0][gb][i] + acc[0][gb][i] + bhv[0][gb][i]);
          float z = sigmoid_fast(xg[1][gb][i] + acc[1][gb][i] + bhv[1][gb][i]);
          float nn = tanh_fast(xg[2][gb][i] + r * (acc[2][gb][i] + bhv[2][gb][i]));
          float h2 = (1.f - z) * nn + z * hprev[gb][i];
          hprev[gb][i] = h2;
          h2v[i] = h2;
        }
        int c0 = (w * 2 + gb) * 16 + krow * 4;
        int kc = c0 >> 5, slot = ((c0 >> 3) & 3) * 16 + col, j0 = c0 & 7;
        short4_t hi4, lo4;
#pragma unroll
        for (int i = 0; i < 4; ++i) {
          unsigned short h = f2bf(h2v[i]);
          hi4[i] = (short)h;
          lo4[i] = (short)f2bf(h2v[i] - bf2f(h));
        }
        *(short4_t*)&hfhi[buf ^ 1][kc][slot][j0] = hi4;
        *(short4_t*)&hflo[buf ^ 1][kc][slot][j0] = lo4;
        *(f32x4*)&out[((size_t)n * B_ + col) * (2 * H_) + dir * H_ + c0] = h2v;
      }
    }
    __syncthreads();
    buf ^= 1;
  }
}

// ---------------------------------------------------------------------------
extern "C" void kernel_launch(void* const* d_in, const int* in_sizes, int n_in,
                              void* d_out, int out_size, void* d_ws, size_t ws_size,
                              hipStream_t stream) {
  const float* pin  = (const float*)d_in[0];
  const int*   mask = (const int*)d_in[1];
  const float* W0   = (const float*)d_in[2];
  const float* vs   = (const float*)d_in[3];
  const float* Wihf = (const float*)d_in[4];
  const float* Whhf = (const float*)d_in[5];
  const float* bihf = (const float*)d_in[6];
  const float* bhhf = (const float*)d_in[7];
  const float* Wihb = (const float*)d_in[8];
  const float* Whhb = (const float*)d_in[9];
  const float* bihb = (const float*)d_in[10];
  const float* bhhb = (const float*)d_in[11];
  float* out = (float*)d_out;
  float* ws = (float*)d_ws;

  float* vpR = ws;                  // 1,024,000
  float* vpT = ws + 1024000;        // 1,024,000
  float* S   = ws + 2048000;        // 8,000,000
  float* m_  = ws + 10048000;       // 8,000
  float* rl_ = ws + 10056000;       // 8,000
  float* rnn = ws + 10064000;       // 4,096,000
  float* xwf = ws + 14160000;       // 3,072,000
  float* xwb = ws + 17232000;       // 3,072,000

  hipLaunchKernelGGL(k_vp, dim3(N_), dim3(256), 0, stream, pin, W0, vpR, vpT);
  hipLaunchKernelGGL(k_scores, dim3(125, 8), dim3(256), 0, stream, vpR, vpT, vs, mask, S);
  hipLaunchKernelGGL(k_rowstats, dim3(N_, 8), dim3(64), 0, stream, S, m_, rl_);
  hipLaunchKernelGGL(k_pv, dim3(63, 8), dim3(256), 0, stream, S, m_, rl_, pin, rnn);
  hipLaunchKernelGGL(k_xw, dim3(N_, 2), dim3(256), 0, stream, rnn, Wihf, bihf, Wihb, bihb, xwf, xwb);
  hipLaunchKernelGGL(k_gru, dim3(2), dim3(256), 0, stream, xwf, xwb, Whhf, Whhb, bhhf, bhhb, out);
}

// Round 5
// 2207.821 us; speedup vs baseline: 1.2055x; 1.2055x over previous
//
#include <hip/hip_runtime.h>

// ---------------------------------------------------------------------------
// SelfMatchEncoder: additive self-attention + bidirectional GRU
// N=1000, B=8, D=256, H=128
// ---------------------------------------------------------------------------

#define N_ 1000
#define B_ 8
#define D_ 256
#define H_ 128
#define G3_ 384  // 3*H
#define KTANH 2.8853900817779268f   // 2*log2(e)
#define LOG2E 1.4426950408889634f

typedef __attribute__((ext_vector_type(8))) short short8_t;
typedef __attribute__((ext_vector_type(4))) short short4_t;
typedef __attribute__((ext_vector_type(4))) float f32x4;

__device__ __forceinline__ unsigned short f2bf(float f) {
  unsigned u = __float_as_uint(f);
  unsigned r = u + 0x7fffu + ((u >> 16) & 1u);
  return (unsigned short)(r >> 16);
}
__device__ __forceinline__ float bf2f(unsigned short b) {
  return __uint_as_float(((unsigned)b) << 16);
}

// ---------------------------------------------------------------------------
// K1: vp[n,b,h] = (sum_d pin[n,b,d]*W0[h,d]) * KTANH  (pre-scaled for exp2)
// ---------------------------------------------------------------------------
__global__ void k_vp(const float* __restrict__ pin, const float* __restrict__ W0,
                     float* __restrict__ vpR, float* __restrict__ vpT) {
  int n = blockIdx.x;
  int tid = threadIdx.x;  // 256
  __shared__ float xs[B_][D_];
  for (int k = 0; k < 8; ++k) {
    int idx = k * 256 + tid;  // 2048
    xs[idx >> 8][idx & 255] = pin[(size_t)n * (B_ * D_) + idx];
  }
  __syncthreads();
  for (int k = 0; k < 4; ++k) {
    int o = k * 256 + tid;  // 1024 = 8b * 128h
    int b = o >> 7, h = o & 127;
    const float4* wr = (const float4*)(W0 + (size_t)h * D_);
    float acc = 0.f;
#pragma unroll 8
    for (int dq = 0; dq < 64; ++dq) {
      float4 w = wr[dq];
      acc += xs[b][dq * 4 + 0] * w.x + xs[b][dq * 4 + 1] * w.y +
             xs[b][dq * 4 + 2] * w.z + xs[b][dq * 4 + 3] * w.w;
    }
    acc *= KTANH;
    vpR[((size_t)b * N_ + n) * H_ + h] = acc;
    vpT[((size_t)b * H_ + h) * N_ + n] = acc;
  }
}

// ---------------------------------------------------------------------------
// K2: S[b,i,j] = VsSum - 2*sum_h vs[h]/(exp2(vp_i+vp_j)+1)  (vp pre-scaled)
// ---------------------------------------------------------------------------
__global__ void k_scores(const float* __restrict__ vpR, const float* __restrict__ vpT,
                         const float* __restrict__ vs, const int* __restrict__ mask,
                         float* __restrict__ S) {
  int b = blockIdx.y;
  int i0 = blockIdx.x * 8;
  int tid = threadIdx.x;  // 256
  __shared__ float vpi[8][H_];
  __shared__ float vss[H_];
  __shared__ float vpj[32][256];
  for (int k = 0; k < 4; ++k) {
    int o = k * 256 + tid;  // 1024
    vpi[o >> 7][o & 127] = vpR[((size_t)b * N_ + i0 + (o >> 7)) * H_ + (o & 127)];
  }
  if (tid < H_) vss[tid] = vs[tid];
  __syncthreads();
  float VsSum = 0.f;
  for (int h = 0; h < H_; ++h) VsSum += vss[h];

  for (int jt = 0; jt < 4; ++jt) {
    int j0 = jt * 256;
    int cnt = min(256, N_ - j0);
    float acc[8] = {0.f, 0.f, 0.f, 0.f, 0.f, 0.f, 0.f, 0.f};
    for (int hc = 0; hc < 4; ++hc) {
      __syncthreads();
      for (int hh = 0; hh < 32; ++hh)
        vpj[hh][tid] = (tid < cnt) ? vpT[((size_t)b * H_ + hc * 32 + hh) * N_ + j0 + tid] : 0.f;
      __syncthreads();
      if (tid < cnt) {
        for (int hh = 0; hh < 32; ++hh) {
          float vj = vpj[hh][tid];
          float vsh = vss[hc * 32 + hh];
#pragma unroll
          for (int i = 0; i < 8; ++i) {
            float e = exp2f(vpi[i][hc * 32 + hh] + vj);
            float r = __builtin_amdgcn_rcpf(e + 1.f);
            acc[i] = fmaf(vsh, r, acc[i]);
          }
        }
      }
    }
    if (tid < cnt) {
      int mj = mask[(size_t)(j0 + tid) * B_ + b];
#pragma unroll
      for (int i = 0; i < 8; ++i)
        S[((size_t)b * N_ + i0 + i) * N_ + j0 + tid] = mj ? -1e30f : (VsSum - 2.f * acc[i]);
    }
  }
}

// ---------------------------------------------------------------------------
// K3: per-row softmax stats (max, 1/sumexp)
// ---------------------------------------------------------------------------
__global__ void k_rowstats(const float* __restrict__ S, float* __restrict__ m_,
                           float* __restrict__ rl_) {
  int i = blockIdx.x, b = blockIdx.y;
  int lane = threadIdx.x;  // 64
  const float* row = S + ((size_t)b * N_ + i) * N_;
  float mx = -3.0e38f;
  for (int j = lane; j < N_; j += 64) mx = fmaxf(mx, row[j]);
  for (int off = 32; off; off >>= 1) mx = fmaxf(mx, __shfl_xor(mx, off));
  float s = 0.f;
  for (int j = lane; j < N_; j += 64) s += __expf(row[j] - mx);
  for (int off = 32; off; off >>= 1) s += __shfl_xor(s, off);
  if (lane == 0) {
    m_[b * N_ + i] = mx;
    rl_[b * N_ + i] = 1.f / s;
  }
}

// ---------------------------------------------------------------------------
// K4: att[i,b,:] = sum_j P[i,j]*pin[j,b,:]; writes rnn_in = [att | pin]
// ---------------------------------------------------------------------------
__global__ void k_pv(const float* __restrict__ S, const float* __restrict__ m_,
                     const float* __restrict__ rl_, const float* __restrict__ pin,
                     float* __restrict__ rnn) {
  int b = blockIdx.y;
  int i0 = blockIdx.x * 16;
  int tid = threadIdx.x;  // 256
  int dg = tid & 63, iq = tid >> 6;
  __shared__ float ps[32][D_];
  __shared__ float PsT[32][16];
  __shared__ float mi[16], ri[16];
  if (tid < 16) {
    int ii = i0 + tid;
    mi[tid] = (ii < N_) ? m_[b * N_ + ii] : 0.f;
    ri[tid] = (ii < N_) ? rl_[b * N_ + ii] : 0.f;
  }
  f32x4 acc[4];
#pragma unroll
  for (int ii = 0; ii < 4; ++ii) acc[ii] = (f32x4){0.f, 0.f, 0.f, 0.f};

  for (int jc = 0; jc < 32; ++jc) {  // 1000 = 31*32 + 8
    int j0 = jc * 32;
    int cj = min(32, N_ - j0);
    __syncthreads();
#pragma unroll
    for (int rr = 0; rr < 8; ++rr) {
      int jj = rr * 4 + iq;
      if (jj < cj)
        *(f32x4*)&ps[jj][dg * 4] =
            *(const f32x4*)&pin[((size_t)(j0 + jj) * B_ + b) * D_ + dg * 4];
    }
#pragma unroll
    for (int k = 0; k < 2; ++k) {
      int v = k * 256 + tid;  // 512 = 32j * 16i
      int jj = v >> 4, il = v & 15;
      float p = 0.f;
      if (jj < cj && i0 + il < N_)
        p = __expf(S[((size_t)b * N_ + i0 + il) * N_ + j0 + jj] - mi[il]) * ri[il];
      PsT[jj][il] = p;
    }
    __syncthreads();
    for (int jj = 0; jj < 32; ++jj) {
      f32x4 pv = *(f32x4*)&ps[jj][dg * 4];
      f32x4 p4 = *(f32x4*)&PsT[jj][iq * 4];
#pragma unroll
      for (int ii = 0; ii < 4; ++ii) acc[ii] += pv * p4[ii];
    }
  }
#pragma unroll
  for (int ii = 0; ii < 4; ++ii) {
    int i = i0 + iq * 4 + ii;
    if (i < N_) {
      size_t base = ((size_t)i * B_ + b) * (2 * D_);
      *(f32x4*)&rnn[base + dg * 4] = acc[ii];
      *(f32x4*)&rnn[base + D_ + dg * 4] =
          *(const f32x4*)&pin[((size_t)i * B_ + b) * D_ + dg * 4];
    }
  }
}

// ---------------------------------------------------------------------------
// K5: xw[n,b,g] = scale(g) * (bias_comb[g] + sum_k rnn[n,b,k]*W_ih[g,k])
// bias_comb = b_ih + b_hh for r,z gates (b_hh_n stays in k_gru, inside r*()).
// scale = LOG2E (r,z) / 2*LOG2E (n) -- pre-scaling for exp2-based gates.
// ---------------------------------------------------------------------------
__global__ void k_xw(const float* __restrict__ rnn, const float* __restrict__ Wf,
                     const float* __restrict__ bf, const float* __restrict__ bhf,
                     const float* __restrict__ Wb, const float* __restrict__ bb,
                     const float* __restrict__ bhb, float* __restrict__ xwf,
                     float* __restrict__ xwb) {
  int n = blockIdx.x;
  int dir = blockIdx.y;
  const float* W = dir ? Wb : Wf;
  const float* bias = dir ? bb : bf;
  const float* bh = dir ? bhb : bhf;
  float* xw = dir ? xwb : xwf;
  int tid = threadIdx.x;  // 256
  __shared__ float xs[B_][2 * D_];
  for (int k = 0; k < 16; ++k) {
    int o = k * 256 + tid;  // 4096
    xs[o >> 9][o & 511] = rnn[(size_t)n * (B_ * 2 * D_) + o];
  }
  __syncthreads();
  for (int gk = 0; gk < 2; ++gk) {
    int g = gk * 256 + tid;
    if (g < G3_) {
      float acc[8];
      float bv = bias[g] + (g < 256 ? bh[g] : 0.f);
      float sc = (g < 256) ? LOG2E : 2.f * LOG2E;
#pragma unroll
      for (int b = 0; b < 8; ++b) acc[b] = bv;
      const float4* wr = (const float4*)(W + (size_t)g * (2 * D_));
      for (int kq = 0; kq < 128; ++kq) {
        float4 w = wr[kq];
#pragma unroll
        for (int b = 0; b < 8; ++b) {
          float4 x = *(const float4*)&xs[b][kq * 4];
          acc[b] += x.x * w.x + x.y * w.y + x.z * w.z + x.w * w.w;
        }
      }
#pragma unroll
      for (int b = 0; b < 8; ++b)
        xw[((size_t)n * B_ + b) * G3_ + g] = acc[b] * sc;
    }
  }
}

// ---------------------------------------------------------------------------
// K6: GRU scan v3. 2 blocks (dir) x 512 threads (8 waves, 2/SIMD).
// Wave w owns h-slice [w*16,(w+1)*16) x 3 gates = 3 MFMA tiles, 36 MFMA/step
// in 9 independent chains of 4 (ILP). Gates fully in-register (exp2-based,
// pre-scaled); h hi/lo bf16 in fragment-order LDS (conflict-free b128);
// double-buffered, ONE barrier per step; xw prefetched one step ahead.
// ---------------------------------------------------------------------------
__global__ __launch_bounds__(512) void k_gru(const float* __restrict__ xwf,
                                             const float* __restrict__ xwb,
                                             const float* __restrict__ Whf,
                                             const float* __restrict__ Whb,
                                             const float* __restrict__ bhf,
                                             const float* __restrict__ bhb,
                                             float* __restrict__ out) {
  int dir = blockIdx.x;
  const float* xw = dir ? xwb : xwf;
  const float* Wh = dir ? Whb : Whf;
  const float* bh = dir ? bhb : bhf;

  __shared__ short hfhi[2][4][64][8];  // buf, kc, slot, j
  __shared__ short hflo[2][4][64][8];

  int tid = threadIdx.x;
  int w = tid >> 6;     // wave 0..7 -> h-slice [w*16, w*16+16)
  int lane = tid & 63;
  int col = lane & 15;  // b (valid < 8); D col and A row index
  int krow = lane >> 4;

  for (int k = tid; k < 2 * 4 * 64 * 8; k += 512) {
    ((short*)hfhi)[k] = 0;
    ((short*)hflo)[k] = 0;
  }

  // W fragments (A operand), pre-scaled: lane holds sc*Wh[g0+col][kc*32+krow*8+j]
  short8_t whi[3][4], wlo[3][4];
#pragma unroll
  for (int gate = 0; gate < 3; ++gate) {
    float sc = (gate == 2) ? 2.f * LOG2E : LOG2E;
    int g0 = gate * 128 + w * 16;
#pragma unroll
    for (int kc = 0; kc < 4; ++kc) {
      const float* wp = Wh + (size_t)(g0 + col) * H_ + kc * 32 + krow * 8;
      short8_t hi8, lo8;
#pragma unroll
      for (int j = 0; j < 8; ++j) {
        float v = wp[j] * sc;
        unsigned short h = f2bf(v);
        hi8[j] = (short)h;
        lo8[j] = (short)f2bf(v - bf2f(h));
      }
      whi[gate][kc] = hi8;
      wlo[gate][kc] = lo8;
    }
  }
  // n-gate hidden bias (scaled); lives inside r*(...) so can't fold into xw
  f32x4 bhn4 = *(const f32x4*)&bh[256 + w * 16 + krow * 4];
  bhn4 *= 2.f * LOG2E;

  f32x4 hprev = {0.f, 0.f, 0.f, 0.f};
  __syncthreads();

  // xw prefetch (t=0)
  f32x4 xg[3], xgn[3];
  if (col < 8) {
    int n0 = dir ? (N_ - 1) : 0;
#pragma unroll
    for (int gate = 0; gate < 3; ++gate)
      xg[gate] = *(const f32x4*)&xw[((size_t)n0 * B_ + col) * G3_ +
                                    gate * 128 + w * 16 + krow * 4];
  }

  int buf = 0;
  for (int t = 0; t < N_; ++t) {
    int n = dir ? (N_ - 1 - t) : t;

    // h fragments (B operand): conflict-free contiguous b128 reads
    short8_t fhi[4], flo[4];
#pragma unroll
    for (int kc = 0; kc < 4; ++kc) {
      fhi[kc] = *(const short8_t*)&hfhi[buf][kc][lane][0];
      flo[kc] = *(const short8_t*)&hflo[buf][kc][lane][0];
    }

    // prefetch next step's xw (used next iteration -> full step to cover)
    if (col < 8 && t + 1 < N_) {
      int n2 = dir ? (N_ - 2 - t) : (t + 1);
#pragma unroll
      for (int gate = 0; gate < 3; ++gate)
        xgn[gate] = *(const f32x4*)&xw[((size_t)n2 * B_ + col) * G3_ +
                                       gate * 128 + w * 16 + krow * 4];
    }

    // hw = h @ W^T : 9 independent MFMA chains of length 4
    f32x4 hwv[3];
#pragma unroll
    for (int gate = 0; gate < 3; ++gate) {
      f32x4 a0 = {0.f, 0.f, 0.f, 0.f};
      f32x4 a1 = {0.f, 0.f, 0.f, 0.f};
      f32x4 a2 = {0.f, 0.f, 0.f, 0.f};
#pragma unroll
      for (int kc = 0; kc < 4; ++kc) {
        a0 = __builtin_amdgcn_mfma_f32_16x16x32_bf16(whi[gate][kc], fhi[kc], a0, 0, 0, 0);
        a1 = __builtin_amdgcn_mfma_f32_16x16x32_bf16(wlo[gate][kc], fhi[kc], a1, 0, 0, 0);
        a2 = __builtin_amdgcn_mfma_f32_16x16x32_bf16(whi[gate][kc], flo[kc], a2, 0, 0, 0);
      }
      hwv[gate] = a0 + a1 + a2;
    }

    // gates in registers (pre-scaled exp2 forms)
    if (col < 8) {
      f32x4 h2v;
#pragma unroll
      for (int i = 0; i < 4; ++i) {
        float er = exp2f(xg[0][i] + hwv[0][i]);
        float r = 1.f - __builtin_amdgcn_rcpf(er + 1.f);
        float ez = exp2f(xg[1][i] + hwv[1][i]);
        float z = 1.f - __builtin_amdgcn_rcpf(ez + 1.f);
        float en = exp2f(fmaf(r, hwv[2][i] + bhn4[i], xg[2][i]));
        float nn = fmaf(-2.f, __builtin_amdgcn_rcpf(en + 1.f), 1.f);
        float h2 = fmaf(z, hprev[i] - nn, nn);
        hprev[i] = h2;
        h2v[i] = h2;
      }
      int c0 = w * 16 + krow * 4;
      int kc = c0 >> 5, slot = ((c0 >> 3) & 3) * 16 + col, j0 = c0 & 7;
      short4_t hi4, lo4;
#pragma unroll
      for (int i = 0; i < 4; ++i) {
        unsigned short h = f2bf(h2v[i]);
        hi4[i] = (short)h;
        lo4[i] = (short)f2bf(h2v[i] - bf2f(h));
      }
      *(short4_t*)&hfhi[buf ^ 1][kc][slot][j0] = hi4;
      *(short4_t*)&hflo[buf ^ 1][kc][slot][j0] = lo4;
      *(f32x4*)&out[((size_t)n * B_ + col) * (2 * H_) + dir * H_ + c0] = h2v;
    }
    __syncthreads();
    buf ^= 1;
#pragma unroll
    for (int gate = 0; gate < 3; ++gate) xg[gate] = xgn[gate];
  }
}

// ---------------------------------------------------------------------------
extern "C" void kernel_launch(void* const* d_in, const int* in_sizes, int n_in,
                              void* d_out, int out_size, void* d_ws, size_t ws_size,
                              hipStream_t stream) {
  const float* pin  = (const float*)d_in[0];
  const int*   mask = (const int*)d_in[1];
  const float* W0   = (const float*)d_in[2];
  const float* vs   = (const float*)d_in[3];
  const float* Wihf = (const float*)d_in[4];
  const float* Whhf = (const float*)d_in[5];
  const float* bihf = (const float*)d_in[6];
  const float* bhhf = (const float*)d_in[7];
  const float* Wihb = (const float*)d_in[8];
  const float* Whhb = (const float*)d_in[9];
  const float* bihb = (const float*)d_in[10];
  const float* bhhb = (const float*)d_in[11];
  float* out = (float*)d_out;
  float* ws = (float*)d_ws;

  float* vpR = ws;                  // 1,024,000
  float* vpT = ws + 1024000;        // 1,024,000
  float* S   = ws + 2048000;        // 8,000,000
  float* m_  = ws + 10048000;       // 8,000
  float* rl_ = ws + 10056000;       // 8,000
  float* rnn = ws + 10064000;       // 4,096,000
  float* xwf = ws + 14160000;       // 3,072,000
  float* xwb = ws + 17232000;       // 3,072,000

  hipLaunchKernelGGL(k_vp, dim3(N_), dim3(256), 0, stream, pin, W0, vpR, vpT);
  hipLaunchKernelGGL(k_scores, dim3(125, 8), dim3(256), 0, stream, vpR, vpT, vs, mask, S);
  hipLaunchKernelGGL(k_rowstats, dim3(N_, 8), dim3(64), 0, stream, S, m_, rl_);
  hipLaunchKernelGGL(k_pv, dim3(63, 8), dim3(256), 0, stream, S, m_, rl_, pin, rnn);
  hipLaunchKernelGGL(k_xw, dim3(N_, 2), dim3(256), 0, stream, rnn, Wihf, bihf, bhhf,
                     Wihb, bihb, bhhb, xwf, xwb);
  hipLaunchKernelGGL(k_gru, dim3(2), dim3(512), 0, stream, xwf, xwb, Whhf, Whhb,
                     bhhf, bhhb, out);
}

// Round 6
// 1673.112 us; speedup vs baseline: 1.5908x; 1.3196x over previous
//
#include <hip/hip_runtime.h>

// ---------------------------------------------------------------------------
// SelfMatchEncoder: additive self-attention + bidirectional GRU
// N=1000, B=8, D=256, H=128
// ---------------------------------------------------------------------------

#define N_ 1000
#define B_ 8
#define D_ 256
#define H_ 128
#define G3_ 384  // 3*H

typedef __attribute__((ext_vector_type(8))) short short8_t;
typedef __attribute__((ext_vector_type(4))) short short4_t;
typedef __attribute__((ext_vector_type(4))) float f32x4;

__device__ __forceinline__ unsigned short f2bf(float f) {
  unsigned u = __float_as_uint(f);
  unsigned r = u + 0x7fffu + ((u >> 16) & 1u);
  return (unsigned short)(r >> 16);
}
__device__ __forceinline__ float bf2f(unsigned short b) {
  return __uint_as_float(((unsigned)b) << 16);
}

// ---------------------------------------------------------------------------
// K1: vp[n,b,h] = 2 * sum_d pin[n,b,d]*W0[h,d]   (x2 folded for tanh-via-exp)
// ---------------------------------------------------------------------------
__global__ void k_vp(const float* __restrict__ pin, const float* __restrict__ W0,
                     float* __restrict__ vpR, float* __restrict__ vpT) {
  int n = blockIdx.x;
  int tid = threadIdx.x;  // 256
  __shared__ float xs[B_][D_];
  for (int k = 0; k < 8; ++k) {
    int idx = k * 256 + tid;  // 2048
    xs[idx >> 8][idx & 255] = pin[(size_t)n * (B_ * D_) + idx];
  }
  __syncthreads();
  for (int k = 0; k < 4; ++k) {
    int o = k * 256 + tid;  // 1024 = 8b * 128h
    int b = o >> 7, h = o & 127;
    const float4* wr = (const float4*)(W0 + (size_t)h * D_);
    float acc = 0.f;
#pragma unroll 8
    for (int dq = 0; dq < 64; ++dq) {
      float4 w = wr[dq];
      acc += xs[b][dq * 4 + 0] * w.x + xs[b][dq * 4 + 1] * w.y +
             xs[b][dq * 4 + 2] * w.z + xs[b][dq * 4 + 3] * w.w;
    }
    acc *= 2.f;
    vpR[((size_t)b * N_ + n) * H_ + h] = acc;
    vpT[((size_t)b * H_ + h) * N_ + n] = acc;
  }
}

// ---------------------------------------------------------------------------
// K2: S[b,i,j] = VsSum - 2*sum_h vs[h]/(exp(vp_i+vp_j)+1)  (vp pre-scaled x2)
// SYMMETRIC: S(i,j)=S(j,i) pre-mask. Block (i0) computes j-tiles >= its own
// and mirror-writes the transpose. Coverage proof: cell (r,c) with c>=i0(r)
// written directly by block(r); c<i0(r) written as mirror by block(c).
// ---------------------------------------------------------------------------
__global__ void k_scores(const float* __restrict__ vpR, const float* __restrict__ vpT,
                         const float* __restrict__ vs, const int* __restrict__ mask,
                         float* __restrict__ S) {
  int b = blockIdx.y;
  int i0 = blockIdx.x * 8;
  int tid = threadIdx.x;  // 256
  __shared__ float vpi[8][H_];
  __shared__ float vss[H_];
  __shared__ int mki[8];
  __shared__ float vpj[32][256];
  for (int k = 0; k < 4; ++k) {
    int o = k * 256 + tid;  // 1024
    vpi[o >> 7][o & 127] = vpR[((size_t)b * N_ + i0 + (o >> 7)) * H_ + (o & 127)];
  }
  if (tid < H_) vss[tid] = vs[tid];
  if (tid < 8) mki[tid] = mask[(size_t)(i0 + tid) * B_ + b];
  __syncthreads();
  float VsSum = 0.f;
  for (int h = 0; h < H_; ++h) VsSum += vss[h];

  int jt0 = i0 >> 8;  // first j-tile overlapping j >= i0
  for (int jt = jt0; jt < 4; ++jt) {
    int j0 = jt * 256;
    int cnt = min(256, N_ - j0);
    float acc[8] = {0.f, 0.f, 0.f, 0.f, 0.f, 0.f, 0.f, 0.f};
    for (int hc = 0; hc < 4; ++hc) {
      __syncthreads();
      for (int hh = 0; hh < 32; ++hh)
        vpj[hh][tid] = (tid < cnt) ? vpT[((size_t)b * H_ + hc * 32 + hh) * N_ + j0 + tid] : 0.f;
      __syncthreads();
      if (tid < cnt) {
        for (int hh = 0; hh < 32; ++hh) {
          float vj = vpj[hh][tid];
          float vsh = vss[hc * 32 + hh];
#pragma unroll
          for (int i = 0; i < 8; ++i) {
            float e = __expf(vpi[i][hc * 32 + hh] + vj);
            float r = __builtin_amdgcn_rcpf(e + 1.f);
            acc[i] = fmaf(vsh, r, acc[i]);
          }
        }
      }
    }
    int j = j0 + tid;
    if (tid < cnt) {
      float val[8];
#pragma unroll
      for (int i = 0; i < 8; ++i) val[i] = VsSum - 2.f * acc[i];
      if (j >= i0) {
        int mj = mask[(size_t)j * B_ + b];
#pragma unroll
        for (int i = 0; i < 8; ++i)
          S[((size_t)b * N_ + i0 + i) * N_ + j] = mj ? -1e30f : val[i];
      }
      if (j >= i0 + 8) {  // mirror write S[j][i0..i0+7], mask per i
        float4 v0, v1;
        v0.x = mki[0] ? -1e30f : val[0];
        v0.y = mki[1] ? -1e30f : val[1];
        v0.z = mki[2] ? -1e30f : val[2];
        v0.w = mki[3] ? -1e30f : val[3];
        v1.x = mki[4] ? -1e30f : val[4];
        v1.y = mki[5] ? -1e30f : val[5];
        v1.z = mki[6] ? -1e30f : val[6];
        v1.w = mki[7] ? -1e30f : val[7];
        float* row = S + ((size_t)b * N_ + j) * N_ + i0;
        *(float4*)row = v0;
        *(float4*)(row + 4) = v1;
      }
    }
  }
}

// ---------------------------------------------------------------------------
// K3: per-row softmax stats (max, 1/sumexp)
// ---------------------------------------------------------------------------
__global__ void k_rowstats(const float* __restrict__ S, float* __restrict__ m_,
                           float* __restrict__ rl_) {
  int i = blockIdx.x, b = blockIdx.y;
  int lane = threadIdx.x;  // 64
  const float* row = S + ((size_t)b * N_ + i) * N_;
  float mx = -3.0e38f;
  for (int j = lane; j < N_; j += 64) mx = fmaxf(mx, row[j]);
  for (int off = 32; off; off >>= 1) mx = fmaxf(mx, __shfl_xor(mx, off));
  float s = 0.f;
  for (int j = lane; j < N_; j += 64) s += __expf(row[j] - mx);
  for (int off = 32; off; off >>= 1) s += __shfl_xor(s, off);
  if (lane == 0) {
    m_[b * N_ + i] = mx;
    rl_[b * N_ + i] = 1.f / s;
  }
}

// ---------------------------------------------------------------------------
// K4: att[i,b,:] = sum_j P[i,j]*pin[j,b,:]; writes rnn_in = [att | pin]
// ---------------------------------------------------------------------------
__global__ void k_pv(const float* __restrict__ S, const float* __restrict__ m_,
                     const float* __restrict__ rl_, const float* __restrict__ pin,
                     float* __restrict__ rnn) {
  int b = blockIdx.y;
  int i0 = blockIdx.x * 16;
  int tid = threadIdx.x;  // 256
  int dg = tid & 63, iq = tid >> 6;
  __shared__ float ps[32][D_];
  __shared__ float PsT[32][16];
  __shared__ float mi[16], ri[16];
  if (tid < 16) {
    int ii = i0 + tid;
    mi[tid] = (ii < N_) ? m_[b * N_ + ii] : 0.f;
    ri[tid] = (ii < N_) ? rl_[b * N_ + ii] : 0.f;
  }
  f32x4 acc[4];
#pragma unroll
  for (int ii = 0; ii < 4; ++ii) acc[ii] = (f32x4){0.f, 0.f, 0.f, 0.f};

  for (int jc = 0; jc < 32; ++jc) {  // 1000 = 31*32 + 8
    int j0 = jc * 32;
    int cj = min(32, N_ - j0);
    __syncthreads();
#pragma unroll
    for (int rr = 0; rr < 8; ++rr) {
      int jj = rr * 4 + iq;
      if (jj < cj)
        *(f32x4*)&ps[jj][dg * 4] =
            *(const f32x4*)&pin[((size_t)(j0 + jj) * B_ + b) * D_ + dg * 4];
    }
#pragma unroll
    for (int k = 0; k < 2; ++k) {
      int v = k * 256 + tid;  // 512 = 32j * 16i
      int jj = v >> 4, il = v & 15;
      float p = 0.f;
      if (jj < cj && i0 + il < N_)
        p = __expf(S[((size_t)b * N_ + i0 + il) * N_ + j0 + jj] - mi[il]) * ri[il];
      PsT[jj][il] = p;
    }
    __syncthreads();
    for (int jj = 0; jj < 32; ++jj) {
      f32x4 pv = *(f32x4*)&ps[jj][dg * 4];
      f32x4 p4 = *(f32x4*)&PsT[jj][iq * 4];
#pragma unroll
      for (int ii = 0; ii < 4; ++ii) acc[ii] += pv * p4[ii];
    }
  }
#pragma unroll
  for (int ii = 0; ii < 4; ++ii) {
    int i = i0 + iq * 4 + ii;
    if (i < N_) {
      size_t base = ((size_t)i * B_ + b) * (2 * D_);
      *(f32x4*)&rnn[base + dg * 4] = acc[ii];
      *(f32x4*)&rnn[base + D_ + dg * 4] =
          *(const f32x4*)&pin[((size_t)i * B_ + b) * D_ + dg * 4];
    }
  }
}

// ---------------------------------------------------------------------------
// K5: xw[n,b,g] = sc(g) * (bias_comb[g] + sum_k rnn[n,b,k]*W_ih[g,k])
// bias_comb = b_ih + b_hh for r,z gates; sc = 1 (r,z) / 2 (n) for exp-gates.
// ---------------------------------------------------------------------------
__global__ void k_xw(const float* __restrict__ rnn, const float* __restrict__ Wf,
                     const float* __restrict__ bf, const float* __restrict__ bhf,
                     const float* __restrict__ Wb, const float* __restrict__ bb,
                     const float* __restrict__ bhb, float* __restrict__ xwf,
                     float* __restrict__ xwb) {
  int n = blockIdx.x;
  int dir = blockIdx.y;
  const float* W = dir ? Wb : Wf;
  const float* bias = dir ? bb : bf;
  const float* bh = dir ? bhb : bhf;
  float* xw = dir ? xwb : xwf;
  int tid = threadIdx.x;  // 256
  __shared__ float xs[B_][2 * D_];
  for (int k = 0; k < 16; ++k) {
    int o = k * 256 + tid;  // 4096
    xs[o >> 9][o & 511] = rnn[(size_t)n * (B_ * 2 * D_) + o];
  }
  __syncthreads();
  for (int gk = 0; gk < 2; ++gk) {
    int g = gk * 256 + tid;
    if (g < G3_) {
      float acc[8];
      float bv = bias[g] + (g < 256 ? bh[g] : 0.f);
      float sc = (g < 256) ? 1.f : 2.f;
#pragma unroll
      for (int b = 0; b < 8; ++b) acc[b] = bv;
      const float4* wr = (const float4*)(W + (size_t)g * (2 * D_));
      for (int kq = 0; kq < 128; ++kq) {
        float4 w = wr[kq];
#pragma unroll
        for (int b = 0; b < 8; ++b) {
          float4 x = *(const float4*)&xs[b][kq * 4];
          acc[b] += x.x * w.x + x.y * w.y + x.z * w.z + x.w * w.w;
        }
      }
#pragma unroll
      for (int b = 0; b < 8; ++b)
        xw[((size_t)n * B_ + b) * G3_ + g] = acc[b] * sc;
    }
  }
}

// ---------------------------------------------------------------------------
// K6: GRU scan v4. 2 blocks (dir) x 512 threads (8 waves, 2/SIMD).
// 2-term split: W = whi+wlo (exact), h single bf16 -> 24 MFMA/wave/step
// (192/block, ~930 cyc issue). Gates in registers via __expf (v_exp).
// h bf16 in fragment-order LDS (conflict-free b128); double-buffered,
// ONE barrier/step; xw prefetched one step ahead.
// ---------------------------------------------------------------------------
__global__ __launch_bounds__(512) void k_gru(const float* __restrict__ xwf,
                                             const float* __restrict__ xwb,
                                             const float* __restrict__ Whf,
                                             const float* __restrict__ Whb,
                                             const float* __restrict__ bhf,
                                             const float* __restrict__ bhb,
                                             float* __restrict__ out) {
  int dir = blockIdx.x;
  const float* xw = dir ? xwb : xwf;
  const float* Wh = dir ? Whb : Whf;
  const float* bh = dir ? bhb : bhf;

  __shared__ short hfh[2][4][64][8];  // buf, kc, slot, j

  int tid = threadIdx.x;
  int w = tid >> 6;     // wave 0..7 -> h-slice [w*16, w*16+16)
  int lane = tid & 63;
  int col = lane & 15;  // b (valid < 8); A row index
  int krow = lane >> 4;

  for (int k = tid; k < 2 * 4 * 64 * 8; k += 512) ((short*)hfh)[k] = 0;

  // W fragments (A operand), gate-scaled: lane holds sc*Wh[g0+col][kc*32+krow*8+j]
  short8_t whi[3][4], wlo[3][4];
#pragma unroll
  for (int gate = 0; gate < 3; ++gate) {
    float sc = (gate == 2) ? 2.f : 1.f;
    int g0 = gate * 128 + w * 16;
#pragma unroll
    for (int kc = 0; kc < 4; ++kc) {
      const float* wp = Wh + (size_t)(g0 + col) * H_ + kc * 32 + krow * 8;
      short8_t hi8, lo8;
#pragma unroll
      for (int j = 0; j < 8; ++j) {
        float v = wp[j] * sc;
        unsigned short h = f2bf(v);
        hi8[j] = (short)h;
        lo8[j] = (short)f2bf(v - bf2f(h));
      }
      whi[gate][kc] = hi8;
      wlo[gate][kc] = lo8;
    }
  }
  // n-gate hidden bias (x2); lives inside r*(...) so can't fold into xw
  f32x4 bhn4 = *(const f32x4*)&bh[256 + w * 16 + krow * 4];
  bhn4 *= 2.f;

  f32x4 hprev = {0.f, 0.f, 0.f, 0.f};
  __syncthreads();

  // xw prefetch (t=0)
  f32x4 xg[3], xgn[3];
  if (col < 8) {
    int n0 = dir ? (N_ - 1) : 0;
#pragma unroll
    for (int gate = 0; gate < 3; ++gate)
      xg[gate] = *(const f32x4*)&xw[((size_t)n0 * B_ + col) * G3_ +
                                    gate * 128 + w * 16 + krow * 4];
  }

  int buf = 0;
  for (int t = 0; t < N_; ++t) {
    int n = dir ? (N_ - 1 - t) : t;

    // h fragments (B operand): conflict-free contiguous b128 reads
    short8_t fh[4];
#pragma unroll
    for (int kc = 0; kc < 4; ++kc)
      fh[kc] = *(const short8_t*)&hfh[buf][kc][lane][0];

    // prefetch next step's xw (full step to cover latency)
    if (col < 8 && t + 1 < N_) {
      int n2 = dir ? (N_ - 2 - t) : (t + 1);
#pragma unroll
      for (int gate = 0; gate < 3; ++gate)
        xgn[gate] = *(const f32x4*)&xw[((size_t)n2 * B_ + col) * G3_ +
                                       gate * 128 + w * 16 + krow * 4];
    }

    // hw = h @ W^T : 6 independent MFMA chains of length 4
    f32x4 hwv[3];
#pragma unroll
    for (int gate = 0; gate < 3; ++gate) {
      f32x4 a0 = {0.f, 0.f, 0.f, 0.f};
      f32x4 a1 = {0.f, 0.f, 0.f, 0.f};
#pragma unroll
      for (int kc = 0; kc < 4; ++kc) {
        a0 = __builtin_amdgcn_mfma_f32_16x16x32_bf16(whi[gate][kc], fh[kc], a0, 0, 0, 0);
        a1 = __builtin_amdgcn_mfma_f32_16x16x32_bf16(wlo[gate][kc], fh[kc], a1, 0, 0, 0);
      }
      hwv[gate] = a0 + a1;
    }

    // gates in registers (exp-based, v_exp via __expf)
    if (col < 8) {
      f32x4 h2v;
#pragma unroll
      for (int i = 0; i < 4; ++i) {
        float er = __expf(xg[0][i] + hwv[0][i]);
        float r = 1.f - __builtin_amdgcn_rcpf(er + 1.f);
        float ez = __expf(xg[1][i] + hwv[1][i]);
        float z = 1.f - __builtin_amdgcn_rcpf(ez + 1.f);
        float en = __expf(fmaf(r, hwv[2][i] + bhn4[i], xg[2][i]));
        float nn = fmaf(-2.f, __builtin_amdgcn_rcpf(en + 1.f), 1.f);
        float h2 = fmaf(z, hprev[i] - nn, nn);
        hprev[i] = h2;
        h2v[i] = h2;
      }
      int c0 = w * 16 + krow * 4;
      int kc = c0 >> 5, slot = ((c0 >> 3) & 3) * 16 + col, j0 = c0 & 7;
      short4_t hi4;
#pragma unroll
      for (int i = 0; i < 4; ++i) hi4[i] = (short)f2bf(h2v[i]);
      *(short4_t*)&hfh[buf ^ 1][kc][slot][j0] = hi4;
      *(f32x4*)&out[((size_t)n * B_ + col) * (2 * H_) + dir * H_ + c0] = h2v;
    }
    __syncthreads();
    buf ^= 1;
#pragma unroll
    for (int gate = 0; gate < 3; ++gate) xg[gate] = xgn[gate];
  }
}

// ---------------------------------------------------------------------------
extern "C" void kernel_launch(void* const* d_in, const int* in_sizes, int n_in,
                              void* d_out, int out_size, void* d_ws, size_t ws_size,
                              hipStream_t stream) {
  const float* pin  = (const float*)d_in[0];
  const int*   mask = (const int*)d_in[1];
  const float* W0   = (const float*)d_in[2];
  const float* vs   = (const float*)d_in[3];
  const float* Wihf = (const float*)d_in[4];
  const float* Whhf = (const float*)d_in[5];
  const float* bihf = (const float*)d_in[6];
  const float* bhhf = (const float*)d_in[7];
  const float* Wihb = (const float*)d_in[8];
  const float* Whhb = (const float*)d_in[9];
  const float* bihb = (const float*)d_in[10];
  const float* bhhb = (const float*)d_in[11];
  float* out = (float*)d_out;
  float* ws = (float*)d_ws;

  float* vpR = ws;                  // 1,024,000
  float* vpT = ws + 1024000;        // 1,024,000
  float* S   = ws + 2048000;        // 8,000,000
  float* m_  = ws + 10048000;       // 8,000
  float* rl_ = ws + 10056000;       // 8,000
  float* rnn = ws + 10064000;       // 4,096,000
  float* xwf = ws + 14160000;       // 3,072,000
  float* xwb = ws + 17232000;       // 3,072,000

  hipLaunchKernelGGL(k_vp, dim3(N_), dim3(256), 0, stream, pin, W0, vpR, vpT);
  hipLaunchKernelGGL(k_scores, dim3(125, 8), dim3(256), 0, stream, vpR, vpT, vs, mask, S);
  hipLaunchKernelGGL(k_rowstats, dim3(N_, 8), dim3(64), 0, stream, S, m_, rl_);
  hipLaunchKernelGGL(k_pv, dim3(63, 8), dim3(256), 0, stream, S, m_, rl_, pin, rnn);
  hipLaunchKernelGGL(k_xw, dim3(N_, 2), dim3(256), 0, stream, rnn, Wihf, bihf, bhhf,
                     Wihb, bihb, bhhb, xwf, xwb);
  hipLaunchKernelGGL(k_gru, dim3(2), dim3(512), 0, stream, xwf, xwb, Whhf, Whhb,
                     bhhf, bhhb, out);
}

// Round 7
// 1615.626 us; speedup vs baseline: 1.6474x; 1.0356x over previous
//
#include <hip/hip_runtime.h>

// ---------------------------------------------------------------------------
// SelfMatchEncoder: additive self-attention + bidirectional GRU
// N=1000, B=8, D=256, H=128
// ---------------------------------------------------------------------------

#define N_ 1000
#define B_ 8
#define D_ 256
#define H_ 128
#define G3_ 384  // 3*H

typedef __attribute__((ext_vector_type(8))) short short8_t;
typedef __attribute__((ext_vector_type(4))) short short4_t;
typedef __attribute__((ext_vector_type(4))) float f32x4;

__device__ __forceinline__ unsigned short f2bf(float f) {
  unsigned u = __float_as_uint(f);
  unsigned r = u + 0x7fffu + ((u >> 16) & 1u);
  return (unsigned short)(r >> 16);
}
__device__ __forceinline__ float bf2f(unsigned short b) {
  return __uint_as_float(((unsigned)b) << 16);
}

// ---------------------------------------------------------------------------
// K1: vp[n,b,h] = 2 * sum_d pin[n,b,d]*W0[h,d]   (x2 folded for tanh-via-exp)
// ---------------------------------------------------------------------------
__global__ void k_vp(const float* __restrict__ pin, const float* __restrict__ W0,
                     float* __restrict__ vpR, float* __restrict__ vpT) {
  int n = blockIdx.x;
  int tid = threadIdx.x;  // 256
  __shared__ float xs[B_][D_];
  for (int k = 0; k < 8; ++k) {
    int idx = k * 256 + tid;  // 2048
    xs[idx >> 8][idx & 255] = pin[(size_t)n * (B_ * D_) + idx];
  }
  __syncthreads();
  for (int k = 0; k < 4; ++k) {
    int o = k * 256 + tid;  // 1024 = 8b * 128h
    int b = o >> 7, h = o & 127;
    const float4* wr = (const float4*)(W0 + (size_t)h * D_);
    float acc = 0.f;
#pragma unroll 8
    for (int dq = 0; dq < 64; ++dq) {
      float4 w = wr[dq];
      acc += xs[b][dq * 4 + 0] * w.x + xs[b][dq * 4 + 1] * w.y +
             xs[b][dq * 4 + 2] * w.z + xs[b][dq * 4 + 3] * w.w;
    }
    acc *= 2.f;
    vpR[((size_t)b * N_ + n) * H_ + h] = acc;
    vpT[((size_t)b * H_ + h) * N_ + n] = acc;
  }
}

// ---------------------------------------------------------------------------
// K2: S[b,i,j] = VsSum - 2*sum_h vs[h]/(exp(vp_i+vp_j)+1)  (vp pre-scaled x2)
// SYMMETRIC pre-mask. One (i-tile, j-tile) pair per block, j-tile >= i-tile;
// mirror-writes the transpose. 317 pairs x 8 batches, uniform work.
// ---------------------------------------------------------------------------
__global__ void k_scores(const float* __restrict__ vpR, const float* __restrict__ vpT,
                         const float* __restrict__ vs, const int* __restrict__ mask,
                         float* __restrict__ S) {
  int b = blockIdx.y;
  int bx = blockIdx.x;  // 0..316 -> (it, jt) with jt >= it>>5
  int it, jt;
  if (bx < 128) { it = bx >> 2; jt = bx & 3; }
  else if (bx < 224) { int r = bx - 128; it = 32 + r / 3; jt = 1 + r % 3; }
  else if (bx < 288) { int r = bx - 224; it = 64 + r / 2; jt = 2 + r % 2; }
  else { it = 96 + (bx - 288); jt = 3; }
  int i0 = it * 8;
  int j0 = jt * 256;
  int tid = threadIdx.x;  // 256

  __shared__ float vpi[8][H_];
  __shared__ float vss[H_];
  __shared__ int mki[8];
  __shared__ float vpj[32][256];
  for (int k = 0; k < 4; ++k) {
    int o = k * 256 + tid;  // 1024
    vpi[o >> 7][o & 127] = vpR[((size_t)b * N_ + i0 + (o >> 7)) * H_ + (o & 127)];
  }
  if (tid < H_) vss[tid] = vs[tid];
  if (tid < 8) mki[tid] = mask[(size_t)(i0 + tid) * B_ + b];
  __syncthreads();
  float VsSum = 0.f;
  for (int h = 0; h < H_; ++h) VsSum += vss[h];

  int cnt = min(256, N_ - j0);
  float acc[8] = {0.f, 0.f, 0.f, 0.f, 0.f, 0.f, 0.f, 0.f};
  for (int hc = 0; hc < 4; ++hc) {
    __syncthreads();
    for (int hh = 0; hh < 32; ++hh)
      vpj[hh][tid] = (tid < cnt) ? vpT[((size_t)b * H_ + hc * 32 + hh) * N_ + j0 + tid] : 0.f;
    __syncthreads();
    if (tid < cnt) {
      for (int hh = 0; hh < 32; ++hh) {
        float vj = vpj[hh][tid];
        float vsh = vss[hc * 32 + hh];
#pragma unroll
        for (int i = 0; i < 8; ++i) {
          float e = __expf(vpi[i][hc * 32 + hh] + vj);
          float r = __builtin_amdgcn_rcpf(e + 1.f);
          acc[i] = fmaf(vsh, r, acc[i]);
        }
      }
    }
  }
  int j = j0 + tid;
  if (tid < cnt) {
    float val[8];
#pragma unroll
    for (int i = 0; i < 8; ++i) val[i] = VsSum - 2.f * acc[i];
    if (j >= i0) {
      int mj = mask[(size_t)j * B_ + b];
#pragma unroll
      for (int i = 0; i < 8; ++i)
        S[((size_t)b * N_ + i0 + i) * N_ + j] = mj ? -1e30f : val[i];
    }
    if (j >= i0 + 8) {  // mirror write S[j][i0..i0+7], mask per i
      float4 v0, v1;
      v0.x = mki[0] ? -1e30f : val[0];
      v0.y = mki[1] ? -1e30f : val[1];
      v0.z = mki[2] ? -1e30f : val[2];
      v0.w = mki[3] ? -1e30f : val[3];
      v1.x = mki[4] ? -1e30f : val[4];
      v1.y = mki[5] ? -1e30f : val[5];
      v1.z = mki[6] ? -1e30f : val[6];
      v1.w = mki[7] ? -1e30f : val[7];
      float* row = S + ((size_t)b * N_ + j) * N_ + i0;
      *(float4*)row = v0;
      *(float4*)(row + 4) = v1;
    }
  }
}

// ---------------------------------------------------------------------------
// K3: per-row softmax stats (max, 1/sumexp)
// ---------------------------------------------------------------------------
__global__ void k_rowstats(const float* __restrict__ S, float* __restrict__ m_,
                           float* __restrict__ rl_) {
  int i = blockIdx.x, b = blockIdx.y;
  int lane = threadIdx.x;  // 64
  const float* row = S + ((size_t)b * N_ + i) * N_;
  float mx = -3.0e38f;
  for (int j = lane; j < N_; j += 64) mx = fmaxf(mx, row[j]);
  for (int off = 32; off; off >>= 1) mx = fmaxf(mx, __shfl_xor(mx, off));
  float s = 0.f;
  for (int j = lane; j < N_; j += 64) s += __expf(row[j] - mx);
  for (int off = 32; off; off >>= 1) s += __shfl_xor(s, off);
  if (lane == 0) {
    m_[b * N_ + i] = mx;
    rl_[b * N_ + i] = 1.f / s;
  }
}

// ---------------------------------------------------------------------------
// K4: att[i,b,:] = sum_j P[i,j]*pin[j,b,:]; writes rnn_in = [att | pin]
// ---------------------------------------------------------------------------
__global__ void k_pv(const float* __restrict__ S, const float* __restrict__ m_,
                     const float* __restrict__ rl_, const float* __restrict__ pin,
                     float* __restrict__ rnn) {
  int b = blockIdx.y;
  int i0 = blockIdx.x * 16;
  int tid = threadIdx.x;  // 256
  int dg = tid & 63, iq = tid >> 6;
  __shared__ float ps[32][D_];
  __shared__ float PsT[32][16];
  __shared__ float mi[16], ri[16];
  if (tid < 16) {
    int ii = i0 + tid;
    mi[tid] = (ii < N_) ? m_[b * N_ + ii] : 0.f;
    ri[tid] = (ii < N_) ? rl_[b * N_ + ii] : 0.f;
  }
  f32x4 acc[4];
#pragma unroll
  for (int ii = 0; ii < 4; ++ii) acc[ii] = (f32x4){0.f, 0.f, 0.f, 0.f};

  for (int jc = 0; jc < 32; ++jc) {  // 1000 = 31*32 + 8
    int j0 = jc * 32;
    int cj = min(32, N_ - j0);
    __syncthreads();
#pragma unroll
    for (int rr = 0; rr < 8; ++rr) {
      int jj = rr * 4 + iq;
      if (jj < cj)
        *(f32x4*)&ps[jj][dg * 4] =
            *(const f32x4*)&pin[((size_t)(j0 + jj) * B_ + b) * D_ + dg * 4];
    }
#pragma unroll
    for (int k = 0; k < 2; ++k) {
      int v = k * 256 + tid;  // 512 = 32j * 16i
      int jj = v >> 4, il = v & 15;
      float p = 0.f;
      if (jj < cj && i0 + il < N_)
        p = __expf(S[((size_t)b * N_ + i0 + il) * N_ + j0 + jj] - mi[il]) * ri[il];
      PsT[jj][il] = p;
    }
    __syncthreads();
    for (int jj = 0; jj < 32; ++jj) {
      f32x4 pv = *(f32x4*)&ps[jj][dg * 4];
      f32x4 p4 = *(f32x4*)&PsT[jj][iq * 4];
#pragma unroll
      for (int ii = 0; ii < 4; ++ii) acc[ii] += pv * p4[ii];
    }
  }
#pragma unroll
  for (int ii = 0; ii < 4; ++ii) {
    int i = i0 + iq * 4 + ii;
    if (i < N_) {
      size_t base = ((size_t)i * B_ + b) * (2 * D_);
      *(f32x4*)&rnn[base + dg * 4] = acc[ii];
      *(f32x4*)&rnn[base + D_ + dg * 4] =
          *(const f32x4*)&pin[((size_t)i * B_ + b) * D_ + dg * 4];
    }
  }
}

// ---------------------------------------------------------------------------
// K5: xw[n,b,g] = sc(g) * (bias_comb[g] + sum_k rnn[n,b,k]*W_ih[g,k])
// bias_comb = b_ih + b_hh for r,z gates; sc = 1 (r,z) / 2 (n) for exp-gates.
// ---------------------------------------------------------------------------
__global__ void k_xw(const float* __restrict__ rnn, const float* __restrict__ Wf,
                     const float* __restrict__ bf, const float* __restrict__ bhf,
                     const float* __restrict__ Wb, const float* __restrict__ bb,
                     const float* __restrict__ bhb, float* __restrict__ xwf,
                     float* __restrict__ xwb) {
  int n = blockIdx.x;
  int dir = blockIdx.y;
  const float* W = dir ? Wb : Wf;
  const float* bias = dir ? bb : bf;
  const float* bh = dir ? bhb : bhf;
  float* xw = dir ? xwb : xwf;
  int tid = threadIdx.x;  // 256
  __shared__ float xs[B_][2 * D_];
  for (int k = 0; k < 16; ++k) {
    int o = k * 256 + tid;  // 4096
    xs[o >> 9][o & 511] = rnn[(size_t)n * (B_ * 2 * D_) + o];
  }
  __syncthreads();
  for (int gk = 0; gk < 2; ++gk) {
    int g = gk * 256 + tid;
    if (g < G3_) {
      float acc[8];
      float bv = bias[g] + (g < 256 ? bh[g] : 0.f);
      float sc = (g < 256) ? 1.f : 2.f;
#pragma unroll
      for (int b = 0; b < 8; ++b) acc[b] = bv;
      const float4* wr = (const float4*)(W + (size_t)g * (2 * D_));
      for (int kq = 0; kq < 128; ++kq) {
        float4 w = wr[kq];
#pragma unroll
        for (int b = 0; b < 8; ++b) {
          float4 x = *(const float4*)&xs[b][kq * 4];
          acc[b] += x.x * w.x + x.y * w.y + x.z * w.z + x.w * w.w;
        }
      }
#pragma unroll
      for (int b = 0; b < 8; ++b)
        xw[((size_t)n * B_ + b) * G3_ + g] = acc[b] * sc;
    }
  }
}

// ---------------------------------------------------------------------------
// K6: GRU scan v5. 2 blocks (dir) x 512 threads (8 waves, 2/SIMD).
// vs v4: (a) loop barrier is raw "s_waitcnt lgkmcnt(0); s_barrier" -- does
// NOT drain vmcnt, so xw prefetch loads stay in flight across the barrier
// (the v4 step was eating its own prefetch's full HBM latency each step);
// (b) xw prefetch deepened to 2 steps (~2 steps of cover > ~900cy HBM miss).
// ---------------------------------------------------------------------------
__global__ __launch_bounds__(512) void k_gru(const float* __restrict__ xwf,
                                             const float* __restrict__ xwb,
                                             const float* __restrict__ Whf,
                                             const float* __restrict__ Whb,
                                             const float* __restrict__ bhf,
                                             const float* __restrict__ bhb,
                                             float* __restrict__ out) {
  int dir = blockIdx.x;
  const float* xw = dir ? xwb : xwf;
  const float* Wh = dir ? Whb : Whf;
  const float* bh = dir ? bhb : bhf;

  __shared__ short hfh[2][4][64][8];  // buf, kc, slot, j

  int tid = threadIdx.x;
  int w = tid >> 6;     // wave 0..7 -> h-slice [w*16, w*16+16)
  int lane = tid & 63;
  int col = lane & 15;  // b (valid < 8); A row index
  int krow = lane >> 4;

  for (int k = tid; k < 2 * 4 * 64 * 8; k += 512) ((short*)hfh)[k] = 0;

  // W fragments (A operand), gate-scaled: lane holds sc*Wh[g0+col][kc*32+krow*8+j]
  short8_t whi[3][4], wlo[3][4];
#pragma unroll
  for (int gate = 0; gate < 3; ++gate) {
    float sc = (gate == 2) ? 2.f : 1.f;
    int g0 = gate * 128 + w * 16;
#pragma unroll
    for (int kc = 0; kc < 4; ++kc) {
      const float* wp = Wh + (size_t)(g0 + col) * H_ + kc * 32 + krow * 8;
      short8_t hi8, lo8;
#pragma unroll
      for (int j = 0; j < 8; ++j) {
        float v = wp[j] * sc;
        unsigned short h = f2bf(v);
        hi8[j] = (short)h;
        lo8[j] = (short)f2bf(v - bf2f(h));
      }
      whi[gate][kc] = hi8;
      wlo[gate][kc] = lo8;
    }
  }
  // n-gate hidden bias (x2); lives inside r*(...) so can't fold into xw
  f32x4 bhn4 = *(const f32x4*)&bh[256 + w * 16 + krow * 4];
  bhn4 *= 2.f;

  f32x4 hprev = {0.f, 0.f, 0.f, 0.f};
  __syncthreads();

  // depth-2 xw prefetch queue: xg = t, xq0 = t+1, xq1 = t+2 (in flight)
  f32x4 xg[3], xq0[3], xq1[3];
  if (col < 8) {
    int n0 = dir ? (N_ - 1) : 0;
    int n1 = dir ? (N_ - 2) : 1;
#pragma unroll
    for (int gate = 0; gate < 3; ++gate) {
      xg[gate] = *(const f32x4*)&xw[((size_t)n0 * B_ + col) * G3_ +
                                    gate * 128 + w * 16 + krow * 4];
      xq0[gate] = *(const f32x4*)&xw[((size_t)n1 * B_ + col) * G3_ +
                                     gate * 128 + w * 16 + krow * 4];
    }
  }

  int buf = 0;
  for (int t = 0; t < N_; ++t) {
    int n = dir ? (N_ - 1 - t) : t;

    // h fragments (B operand): conflict-free contiguous b128 reads
    short8_t fh[4];
#pragma unroll
    for (int kc = 0; kc < 4; ++kc)
      fh[kc] = *(const short8_t*)&hfh[buf][kc][lane][0];

    // issue prefetch for t+2 (2 steps of latency cover)
    if (col < 8 && t + 2 < N_) {
      int n2 = dir ? (N_ - 3 - t) : (t + 2);
#pragma unroll
      for (int gate = 0; gate < 3; ++gate)
        xq1[gate] = *(const f32x4*)&xw[((size_t)n2 * B_ + col) * G3_ +
                                       gate * 128 + w * 16 + krow * 4];
    }

    // hw = h @ W^T : 6 independent MFMA chains of length 4
    f32x4 hwv[3];
#pragma unroll
    for (int gate = 0; gate < 3; ++gate) {
      f32x4 a0 = {0.f, 0.f, 0.f, 0.f};
      f32x4 a1 = {0.f, 0.f, 0.f, 0.f};
#pragma unroll
      for (int kc = 0; kc < 4; ++kc) {
        a0 = __builtin_amdgcn_mfma_f32_16x16x32_bf16(whi[gate][kc], fh[kc], a0, 0, 0, 0);
        a1 = __builtin_amdgcn_mfma_f32_16x16x32_bf16(wlo[gate][kc], fh[kc], a1, 0, 0, 0);
      }
      hwv[gate] = a0 + a1;
    }

    // gates in registers (exp-based, v_exp via __expf)
    if (col < 8) {
      f32x4 h2v;
#pragma unroll
      for (int i = 0; i < 4; ++i) {
        float er = __expf(xg[0][i] + hwv[0][i]);
        float r = 1.f - __builtin_amdgcn_rcpf(er + 1.f);
        float ez = __expf(xg[1][i] + hwv[1][i]);
        float z = 1.f - __builtin_amdgcn_rcpf(ez + 1.f);
        float en = __expf(fmaf(r, hwv[2][i] + bhn4[i], xg[2][i]));
        float nn = fmaf(-2.f, __builtin_amdgcn_rcpf(en + 1.f), 1.f);
        float h2 = fmaf(z, hprev[i] - nn, nn);
        hprev[i] = h2;
        h2v[i] = h2;
      }
      int c0 = w * 16 + krow * 4;
      int kc = c0 >> 5, slot = ((c0 >> 3) & 3) * 16 + col, j0 = c0 & 7;
      short4_t hi4;
#pragma unroll
      for (int i = 0; i < 4; ++i) hi4[i] = (short)f2bf(h2v[i]);
      *(short4_t*)&hfh[buf ^ 1][kc][slot][j0] = hi4;
      *(f32x4*)&out[((size_t)n * B_ + col) * (2 * H_) + dir * H_ + c0] = h2v;
    }
    // LDS-only barrier: do NOT drain vmcnt -> prefetch stays in flight
    asm volatile("s_waitcnt lgkmcnt(0)\n\ts_barrier" ::: "memory");
    buf ^= 1;
#pragma unroll
    for (int gate = 0; gate < 3; ++gate) {
      xg[gate] = xq0[gate];
      xq0[gate] = xq1[gate];
    }
  }
}

// ---------------------------------------------------------------------------
extern "C" void kernel_launch(void* const* d_in, const int* in_sizes, int n_in,
                              void* d_out, int out_size, void* d_ws, size_t ws_size,
                              hipStream_t stream) {
  const float* pin  = (const float*)d_in[0];
  const int*   mask = (const int*)d_in[1];
  const float* W0   = (const float*)d_in[2];
  const float* vs   = (const float*)d_in[3];
  const float* Wihf = (const float*)d_in[4];
  const float* Whhf = (const float*)d_in[5];
  const float* bihf = (const float*)d_in[6];
  const float* bhhf = (const float*)d_in[7];
  const float* Wihb = (const float*)d_in[8];
  const float* Whhb = (const float*)d_in[9];
  const float* bihb = (const float*)d_in[10];
  const float* bhhb = (const float*)d_in[11];
  float* out = (float*)d_out;
  float* ws = (float*)d_ws;

  float* vpR = ws;                  // 1,024,000
  float* vpT = ws + 1024000;        // 1,024,000
  float* S   = ws + 2048000;        // 8,000,000
  float* m_  = ws + 10048000;       // 8,000
  float* rl_ = ws + 10056000;       // 8,000
  float* rnn = ws + 10064000;       // 4,096,000
  float* xwf = ws + 14160000;       // 3,072,000
  float* xwb = ws + 17232000;       // 3,072,000

  hipLaunchKernelGGL(k_vp, dim3(N_), dim3(256), 0, stream, pin, W0, vpR, vpT);
  hipLaunchKernelGGL(k_scores, dim3(317, 8), dim3(256), 0, stream, vpR, vpT, vs, mask, S);
  hipLaunchKernelGGL(k_rowstats, dim3(N_, 8), dim3(64), 0, stream, S, m_, rl_);
  hipLaunchKernelGGL(k_pv, dim3(63, 8), dim3(256), 0, stream, S, m_, rl_, pin, rnn);
  hipLaunchKernelGGL(k_xw, dim3(N_, 2), dim3(256), 0, stream, rnn, Wihf, bihf, bhhf,
                     Wihb, bihb, bhhb, xwf, xwb);
  hipLaunchKernelGGL(k_gru, dim3(2), dim3(512), 0, stream, xwf, xwb, Whhf, Whhb,
                     bhhf, bhhb, out);
}

// Round 8
// 1541.446 us; speedup vs baseline: 1.7267x; 1.0481x over previous
//
#include <hip/hip_runtime.h>

// ---------------------------------------------------------------------------
// SelfMatchEncoder: additive self-attention + bidirectional GRU
// N=1000, B=8, D=256, H=128
// ---------------------------------------------------------------------------

#define N_ 1000
#define B_ 8
#define D_ 256
#define H_ 128
#define G3_ 384  // 3*H

typedef __attribute__((ext_vector_type(8))) short short8_t;
typedef __attribute__((ext_vector_type(4))) short short4_t;
typedef __attribute__((ext_vector_type(4))) float f32x4;

__device__ __forceinline__ unsigned short f2bf(float f) {
  unsigned u = __float_as_uint(f);
  unsigned r = u + 0x7fffu + ((u >> 16) & 1u);
  return (unsigned short)(r >> 16);
}
__device__ __forceinline__ float bf2f(unsigned short b) {
  return __uint_as_float(((unsigned)b) << 16);
}

// ---------------------------------------------------------------------------
// K1: vp[n,b,h] = 2 * sum_d pin[n,b,d]*W0[h,d]   (x2 folded for tanh-via-exp)
// ---------------------------------------------------------------------------
__global__ void k_vp(const float* __restrict__ pin, const float* __restrict__ W0,
                     float* __restrict__ vpR, float* __restrict__ vpT) {
  int n = blockIdx.x;
  int tid = threadIdx.x;  // 256
  __shared__ float xs[B_][D_];
  for (int k = 0; k < 8; ++k) {
    int idx = k * 256 + tid;  // 2048
    xs[idx >> 8][idx & 255] = pin[(size_t)n * (B_ * D_) + idx];
  }
  __syncthreads();
  for (int k = 0; k < 4; ++k) {
    int o = k * 256 + tid;  // 1024 = 8b * 128h
    int b = o >> 7, h = o & 127;
    const float4* wr = (const float4*)(W0 + (size_t)h * D_);
    float acc = 0.f;
#pragma unroll 8
    for (int dq = 0; dq < 64; ++dq) {
      float4 w = wr[dq];
      acc += xs[b][dq * 4 + 0] * w.x + xs[b][dq * 4 + 1] * w.y +
             xs[b][dq * 4 + 2] * w.z + xs[b][dq * 4 + 3] * w.w;
    }
    acc *= 2.f;
    vpR[((size_t)b * N_ + n) * H_ + h] = acc;
    vpT[((size_t)b * H_ + h) * N_ + n] = acc;
  }
}

// ---------------------------------------------------------------------------
// K2: S[b,i,j] = VsSum - 2*sum_h vs[h]/(exp(vp_i+vp_j)+1)  (vp pre-scaled x2)
// SYMMETRIC pre-mask. One (i-tile, j-tile) pair per block, j-tile >= i-tile;
// mirror-writes the transpose. 317 pairs x 8 batches, uniform work.
// ---------------------------------------------------------------------------
__global__ void k_scores(const float* __restrict__ vpR, const float* __restrict__ vpT,
                         const float* __restrict__ vs, const int* __restrict__ mask,
                         float* __restrict__ S) {
  int b = blockIdx.y;
  int bx = blockIdx.x;  // 0..316 -> (it, jt) with jt >= it>>5
  int it, jt;
  if (bx < 128) { it = bx >> 2; jt = bx & 3; }
  else if (bx < 224) { int r = bx - 128; it = 32 + r / 3; jt = 1 + r % 3; }
  else if (bx < 288) { int r = bx - 224; it = 64 + r / 2; jt = 2 + r % 2; }
  else { it = 96 + (bx - 288); jt = 3; }
  int i0 = it * 8;
  int j0 = jt * 256;
  int tid = threadIdx.x;  // 256

  __shared__ float vpi[8][H_];
  __shared__ float vss[H_];
  __shared__ int mki[8];
  __shared__ float vpj[32][256];
  for (int k = 0; k < 4; ++k) {
    int o = k * 256 + tid;  // 1024
    vpi[o >> 7][o & 127] = vpR[((size_t)b * N_ + i0 + (o >> 7)) * H_ + (o & 127)];
  }
  if (tid < H_) vss[tid] = vs[tid];
  if (tid < 8) mki[tid] = mask[(size_t)(i0 + tid) * B_ + b];
  __syncthreads();
  float VsSum = 0.f;
  for (int h = 0; h < H_; ++h) VsSum += vss[h];

  int cnt = min(256, N_ - j0);
  float acc[8] = {0.f, 0.f, 0.f, 0.f, 0.f, 0.f, 0.f, 0.f};
  for (int hc = 0; hc < 4; ++hc) {
    __syncthreads();
    for (int hh = 0; hh < 32; ++hh)
      vpj[hh][tid] = (tid < cnt) ? vpT[((size_t)b * H_ + hc * 32 + hh) * N_ + j0 + tid] : 0.f;
    __syncthreads();
    if (tid < cnt) {
      for (int hh = 0; hh < 32; ++hh) {
        float vj = vpj[hh][tid];
        float vsh = vss[hc * 32 + hh];
#pragma unroll
        for (int i = 0; i < 8; ++i) {
          float e = __expf(vpi[i][hc * 32 + hh] + vj);
          float r = __builtin_amdgcn_rcpf(e + 1.f);
          acc[i] = fmaf(vsh, r, acc[i]);
        }
      }
    }
  }
  int j = j0 + tid;
  if (tid < cnt) {
    float val[8];
#pragma unroll
    for (int i = 0; i < 8; ++i) val[i] = VsSum - 2.f * acc[i];
    if (j >= i0) {
      int mj = mask[(size_t)j * B_ + b];
#pragma unroll
      for (int i = 0; i < 8; ++i)
        S[((size_t)b * N_ + i0 + i) * N_ + j] = mj ? -1e30f : val[i];
    }
    if (j >= i0 + 8) {  // mirror write S[j][i0..i0+7], mask per i
      float4 v0, v1;
      v0.x = mki[0] ? -1e30f : val[0];
      v0.y = mki[1] ? -1e30f : val[1];
      v0.z = mki[2] ? -1e30f : val[2];
      v0.w = mki[3] ? -1e30f : val[3];
      v1.x = mki[4] ? -1e30f : val[4];
      v1.y = mki[5] ? -1e30f : val[5];
      v1.z = mki[6] ? -1e30f : val[6];
      v1.w = mki[7] ? -1e30f : val[7];
      float* row = S + ((size_t)b * N_ + j) * N_ + i0;
      *(float4*)row = v0;
      *(float4*)(row + 4) = v1;
    }
  }
}

// ---------------------------------------------------------------------------
// K3: per-row softmax stats (max, 1/sumexp)
// ---------------------------------------------------------------------------
__global__ void k_rowstats(const float* __restrict__ S, float* __restrict__ m_,
                           float* __restrict__ rl_) {
  int i = blockIdx.x, b = blockIdx.y;
  int lane = threadIdx.x;  // 64
  const float* row = S + ((size_t)b * N_ + i) * N_;
  float mx = -3.0e38f;
  for (int j = lane; j < N_; j += 64) mx = fmaxf(mx, row[j]);
  for (int off = 32; off; off >>= 1) mx = fmaxf(mx, __shfl_xor(mx, off));
  float s = 0.f;
  for (int j = lane; j < N_; j += 64) s += __expf(row[j] - mx);
  for (int off = 32; off; off >>= 1) s += __shfl_xor(s, off);
  if (lane == 0) {
    m_[b * N_ + i] = mx;
    rl_[b * N_ + i] = 1.f / s;
  }
}

// ---------------------------------------------------------------------------
// K4: att[i,b,:] = sum_j P[i,j]*pin[j,b,:]; writes rnn_in = [att | pin]
// ---------------------------------------------------------------------------
__global__ void k_pv(const float* __restrict__ S, const float* __restrict__ m_,
                     const float* __restrict__ rl_, const float* __restrict__ pin,
                     float* __restrict__ rnn) {
  int b = blockIdx.y;
  int i0 = blockIdx.x * 16;
  int tid = threadIdx.x;  // 256
  int dg = tid & 63, iq = tid >> 6;
  __shared__ float ps[32][D_];
  __shared__ float PsT[32][16];
  __shared__ float mi[16], ri[16];
  if (tid < 16) {
    int ii = i0 + tid;
    mi[tid] = (ii < N_) ? m_[b * N_ + ii] : 0.f;
    ri[tid] = (ii < N_) ? rl_[b * N_ + ii] : 0.f;
  }
  f32x4 acc[4];
#pragma unroll
  for (int ii = 0; ii < 4; ++ii) acc[ii] = (f32x4){0.f, 0.f, 0.f, 0.f};

  for (int jc = 0; jc < 32; ++jc) {  // 1000 = 31*32 + 8
    int j0 = jc * 32;
    int cj = min(32, N_ - j0);
    __syncthreads();
#pragma unroll
    for (int rr = 0; rr < 8; ++rr) {
      int jj = rr * 4 + iq;
      if (jj < cj)
        *(f32x4*)&ps[jj][dg * 4] =
            *(const f32x4*)&pin[((size_t)(j0 + jj) * B_ + b) * D_ + dg * 4];
    }
#pragma unroll
    for (int k = 0; k < 2; ++k) {
      int v = k * 256 + tid;  // 512 = 32j * 16i
      int jj = v >> 4, il = v & 15;
      float p = 0.f;
      if (jj < cj && i0 + il < N_)
        p = __expf(S[((size_t)b * N_ + i0 + il) * N_ + j0 + jj] - mi[il]) * ri[il];
      PsT[jj][il] = p;
    }
    __syncthreads();
    for (int jj = 0; jj < 32; ++jj) {
      f32x4 pv = *(f32x4*)&ps[jj][dg * 4];
      f32x4 p4 = *(f32x4*)&PsT[jj][iq * 4];
#pragma unroll
      for (int ii = 0; ii < 4; ++ii) acc[ii] += pv * p4[ii];
    }
  }
#pragma unroll
  for (int ii = 0; ii < 4; ++ii) {
    int i = i0 + iq * 4 + ii;
    if (i < N_) {
      size_t base = ((size_t)i * B_ + b) * (2 * D_);
      *(f32x4*)&rnn[base + dg * 4] = acc[ii];
      *(f32x4*)&rnn[base + D_ + dg * 4] =
          *(const f32x4*)&pin[((size_t)i * B_ + b) * D_ + dg * 4];
    }
  }
}

// ---------------------------------------------------------------------------
// K5 v2: xw[n,b,g] = sc(g) * (bias_comb[g] + sum_k rnn[n,b,k]*W_ih[g,k])
// 192 threads, 2 g-rows/thread (gA=tid, gB=tid+192): each wave-uniform LDS
// x-read now serves 2 g (2.7x fewer ds instrs -- k_xw was LDS-pipe-bound).
// ---------------------------------------------------------------------------
__global__ void k_xw(const float* __restrict__ rnn, const float* __restrict__ Wf,
                     const float* __restrict__ bf, const float* __restrict__ bhf,
                     const float* __restrict__ Wb, const float* __restrict__ bb,
                     const float* __restrict__ bhb, float* __restrict__ xwf,
                     float* __restrict__ xwb) {
  int n = blockIdx.x;
  int dir = blockIdx.y;
  const float* W = dir ? Wb : Wf;
  const float* bias = dir ? bb : bf;
  const float* bh = dir ? bhb : bhf;
  float* xw = dir ? xwb : xwf;
  int tid = threadIdx.x;  // 192
  __shared__ float xs[B_][2 * D_];
  for (int o = tid; o < B_ * 2 * D_; o += 192)
    ((float*)xs)[o] = rnn[(size_t)n * (B_ * 2 * D_) + o];
  __syncthreads();

  int gA = tid, gB = tid + 192;
  float bvA = bias[gA] + bh[gA];                       // gA < 192 -> always r/z region
  float bvB = bias[gB] + (gB < 256 ? bh[gB] : 0.f);
  float scB = (gB < 256) ? 1.f : 2.f;
  float accA[8], accB[8];
#pragma unroll
  for (int b = 0; b < 8; ++b) { accA[b] = bvA; accB[b] = bvB; }
  const float4* wrA = (const float4*)(W + (size_t)gA * (2 * D_));
  const float4* wrB = (const float4*)(W + (size_t)gB * (2 * D_));
  for (int kq = 0; kq < 128; ++kq) {
    float4 wA = wrA[kq];
    float4 wB = wrB[kq];
#pragma unroll
    for (int b = 0; b < 8; ++b) {
      f32x4 x = *(const f32x4*)&xs[b][kq * 4];
      accA[b] += x[0] * wA.x + x[1] * wA.y + x[2] * wA.z + x[3] * wA.w;
      accB[b] += x[0] * wB.x + x[1] * wB.y + x[2] * wB.z + x[3] * wB.w;
    }
  }
#pragma unroll
  for (int b = 0; b < 8; ++b) {
    xw[((size_t)n * B_ + b) * G3_ + gA] = accA[b];
    xw[((size_t)n * B_ + b) * G3_ + gB] = accB[b] * scB;
  }
}

// ---------------------------------------------------------------------------
// K6: GRU scan v6. 2 blocks (dir) x 512 threads (8 waves, 2/SIMD).
// vs v5: scan UNROLLED x4 with 4 independent xw register sets -- slot s
// consumes xsq[s] then reloads it for t+4 (no cross-slot register moves, so
// no forced vmcnt(0) drain; loads stay in flight ~4 steps). v4/v5's register
// queue (xq0=xq1) made the compiler wait for the current step's own load.
// ---------------------------------------------------------------------------
__global__ __launch_bounds__(512) void k_gru(const float* __restrict__ xwf,
                                             const float* __restrict__ xwb,
                                             const float* __restrict__ Whf,
                                             const float* __restrict__ Whb,
                                             const float* __restrict__ bhf,
                                             const float* __restrict__ bhb,
                                             float* __restrict__ out) {
  int dir = blockIdx.x;
  const float* xw = dir ? xwb : xwf;
  const float* Wh = dir ? Whb : Whf;
  const float* bh = dir ? bhb : bhf;

  __shared__ short hfh[2][4][64][8];  // buf, kc, slot, j

  int tid = threadIdx.x;
  int w = tid >> 6;     // wave 0..7 -> h-slice [w*16, w*16+16)
  int lane = tid & 63;
  int col = lane & 15;  // b (valid < 8); A row index
  int krow = lane >> 4;

  for (int k = tid; k < 2 * 4 * 64 * 8; k += 512) ((short*)hfh)[k] = 0;

  // W fragments (A operand), gate-scaled: lane holds sc*Wh[g0+col][kc*32+krow*8+j]
  short8_t whi[3][4], wlo[3][4];
#pragma unroll
  for (int gate = 0; gate < 3; ++gate) {
    float sc = (gate == 2) ? 2.f : 1.f;
    int g0 = gate * 128 + w * 16;
#pragma unroll
    for (int kc = 0; kc < 4; ++kc) {
      const float* wp = Wh + (size_t)(g0 + col) * H_ + kc * 32 + krow * 8;
      short8_t hi8, lo8;
#pragma unroll
      for (int j = 0; j < 8; ++j) {
        float v = wp[j] * sc;
        unsigned short h = f2bf(v);
        hi8[j] = (short)h;
        lo8[j] = (short)f2bf(v - bf2f(h));
      }
      whi[gate][kc] = hi8;
      wlo[gate][kc] = lo8;
    }
  }
  // n-gate hidden bias (x2); lives inside r*(...) so can't fold into xw
  f32x4 bhn4 = *(const f32x4*)&bh[256 + w * 16 + krow * 4];
  bhn4 *= 2.f;

  f32x4 hprev = {0.f, 0.f, 0.f, 0.f};
  __syncthreads();

  // 4 independent prefetch slots; slot s holds xw for steps t == s (mod 4)
  f32x4 xsq[4][3];
  if (col < 8) {
#pragma unroll
    for (int s = 0; s < 4; ++s) {
      int ns = dir ? (N_ - 1 - s) : s;
#pragma unroll
      for (int gate = 0; gate < 3; ++gate)
        xsq[s][gate] = *(const f32x4*)&xw[((size_t)ns * B_ + col) * G3_ +
                                          gate * 128 + w * 16 + krow * 4];
    }
  }

#define STEP(T, RBUF, S)                                                       \
  do {                                                                         \
    int t_ = (T);                                                              \
    int n_ = dir ? (N_ - 1 - t_) : t_;                                         \
    short8_t fh[4];                                                            \
    _Pragma("unroll") for (int kc = 0; kc < 4; ++kc)                           \
        fh[kc] = *(const short8_t*)&hfh[RBUF][kc][lane][0];                    \
    f32x4 hwv[3];                                                              \
    _Pragma("unroll") for (int gate = 0; gate < 3; ++gate) {                   \
      f32x4 a0 = {0.f, 0.f, 0.f, 0.f};                                         \
      f32x4 a1 = {0.f, 0.f, 0.f, 0.f};                                         \
      _Pragma("unroll") for (int kc = 0; kc < 4; ++kc) {                       \
        a0 = __builtin_amdgcn_mfma_f32_16x16x32_bf16(whi[gate][kc], fh[kc],    \
                                                     a0, 0, 0, 0);             \
        a1 = __builtin_amdgcn_mfma_f32_16x16x32_bf16(wlo[gate][kc], fh[kc],    \
                                                     a1, 0, 0, 0);             \
      }                                                                        \
      hwv[gate] = a0 + a1;                                                     \
    }                                                                          \
    if (col < 8) {                                                             \
      f32x4 h2v;                                                               \
      _Pragma("unroll") for (int i = 0; i < 4; ++i) {                          \
        float er = __expf(xsq[S][0][i] + hwv[0][i]);                           \
        float r = 1.f - __builtin_amdgcn_rcpf(er + 1.f);                       \
        float ez = __expf(xsq[S][1][i] + hwv[1][i]);                           \
        float z = 1.f - __builtin_amdgcn_rcpf(ez + 1.f);                       \
        float en = __expf(fmaf(r, hwv[2][i] + bhn4[i], xsq[S][2][i]));         \
        float nn = fmaf(-2.f, __builtin_amdgcn_rcpf(en + 1.f), 1.f);           \
        float h2 = fmaf(z, hprev[i] - nn, nn);                                 \
        hprev[i] = h2;                                                         \
        h2v[i] = h2;                                                           \
      }                                                                        \
      int c0 = w * 16 + krow * 4;                                              \
      int kc_ = c0 >> 5, slot_ = ((c0 >> 3) & 3) * 16 + col, j0_ = c0 & 7;     \
      short4_t hi4;                                                            \
      _Pragma("unroll") for (int i = 0; i < 4; ++i)                            \
          hi4[i] = (short)f2bf(h2v[i]);                                        \
      *(short4_t*)&hfh[(RBUF) ^ 1][kc_][slot_][j0_] = hi4;                     \
      *(f32x4*)&out[((size_t)n_ * B_ + col) * (2 * H_) + dir * H_ + c0] = h2v; \
      int tn_ = t_ + 4;                                                        \
      int nn_ = (tn_ < N_) ? (dir ? (N_ - 1 - tn_) : tn_) : n_;                \
      _Pragma("unroll") for (int gate = 0; gate < 3; ++gate)                   \
          xsq[S][gate] = *(const f32x4*)&xw[((size_t)nn_ * B_ + col) * G3_ +   \
                                            gate * 128 + w * 16 + krow * 4];   \
    }                                                                          \
    asm volatile("s_waitcnt lgkmcnt(0)\n\ts_barrier" ::: "memory");            \
  } while (0)

  for (int t4 = 0; t4 < N_; t4 += 4) {
    STEP(t4 + 0, 0, 0);
    STEP(t4 + 1, 1, 1);
    STEP(t4 + 2, 0, 2);
    STEP(t4 + 3, 1, 3);
  }
#undef STEP
}

// ---------------------------------------------------------------------------
extern "C" void kernel_launch(void* const* d_in, const int* in_sizes, int n_in,
                              void* d_out, int out_size, void* d_ws, size_t ws_size,
                              hipStream_t stream) {
  const float* pin  = (const float*)d_in[0];
  const int*   mask = (const int*)d_in[1];
  const float* W0   = (const float*)d_in[2];
  const float* vs   = (const float*)d_in[3];
  const float* Wihf = (const float*)d_in[4];
  const float* Whhf = (const float*)d_in[5];
  const float* bihf = (const float*)d_in[6];
  const float* bhhf = (const float*)d_in[7];
  const float* Wihb = (const float*)d_in[8];
  const float* Whhb = (const float*)d_in[9];
  const float* bihb = (const float*)d_in[10];
  const float* bhhb = (const float*)d_in[11];
  float* out = (float*)d_out;
  float* ws = (float*)d_ws;

  float* vpR = ws;                  // 1,024,000
  float* vpT = ws + 1024000;        // 1,024,000
  float* S   = ws + 2048000;        // 8,000,000
  float* m_  = ws + 10048000;       // 8,000
  float* rl_ = ws + 10056000;       // 8,000
  float* rnn = ws + 10064000;       // 4,096,000
  float* xwf = ws + 14160000;       // 3,072,000
  float* xwb = ws + 17232000;       // 3,072,000

  hipLaunchKernelGGL(k_vp, dim3(N_), dim3(256), 0, stream, pin, W0, vpR, vpT);
  hipLaunchKernelGGL(k_scores, dim3(317, 8), dim3(256), 0, stream, vpR, vpT, vs, mask, S);
  hipLaunchKernelGGL(k_rowstats, dim3(N_, 8), dim3(64), 0, stream, S, m_, rl_);
  hipLaunchKernelGGL(k_pv, dim3(63, 8), dim3(256), 0, stream, S, m_, rl_, pin, rnn);
  hipLaunchKernelGGL(k_xw, dim3(N_, 2), dim3(192), 0, stream, rnn, Wihf, bihf, bhhf,
                     Wihb, bihb, bhhb, xwf, xwb);
  hipLaunchKernelGGL(k_gru, dim3(2), dim3(512), 0, stream, xwf, xwb, Whhf, Whhb,
                     bhhf, bhhb, out);
}

// Round 9
// 1339.157 us; speedup vs baseline: 1.9875x; 1.1511x over previous
//
#include <hip/hip_runtime.h>

// ---------------------------------------------------------------------------
// SelfMatchEncoder: additive self-attention + bidirectional GRU
// N=1000, B=8, D=256, H=128
// ---------------------------------------------------------------------------

#define N_ 1000
#define B_ 8
#define D_ 256
#define H_ 128
#define G3_ 384  // 3*H

typedef __attribute__((ext_vector_type(8))) short short8_t;
typedef __attribute__((ext_vector_type(4))) short short4_t;
typedef __attribute__((ext_vector_type(4))) float f32x4;

__device__ __forceinline__ unsigned short f2bf(float f) {
  unsigned u = __float_as_uint(f);
  unsigned r = u + 0x7fffu + ((u >> 16) & 1u);
  return (unsigned short)(r >> 16);
}
__device__ __forceinline__ float bf2f(unsigned short b) {
  return __uint_as_float(((unsigned)b) << 16);
}

// ---------------------------------------------------------------------------
// K1: vp[n,b,h] = 2 * sum_d pin[n,b,d]*W0[h,d]   (x2 folded for tanh-via-exp)
// ---------------------------------------------------------------------------
__global__ void k_vp(const float* __restrict__ pin, const float* __restrict__ W0,
                     float* __restrict__ vpR, float* __restrict__ vpT) {
  int n = blockIdx.x;
  int tid = threadIdx.x;  // 256
  __shared__ float xs[B_][D_];
  for (int k = 0; k < 8; ++k) {
    int idx = k * 256 + tid;  // 2048
    xs[idx >> 8][idx & 255] = pin[(size_t)n * (B_ * D_) + idx];
  }
  __syncthreads();
  for (int k = 0; k < 4; ++k) {
    int o = k * 256 + tid;  // 1024 = 8b * 128h
    int b = o >> 7, h = o & 127;
    const float4* wr = (const float4*)(W0 + (size_t)h * D_);
    float acc = 0.f;
#pragma unroll 8
    for (int dq = 0; dq < 64; ++dq) {
      float4 w = wr[dq];
      acc += xs[b][dq * 4 + 0] * w.x + xs[b][dq * 4 + 1] * w.y +
             xs[b][dq * 4 + 2] * w.z + xs[b][dq * 4 + 3] * w.w;
    }
    acc *= 2.f;
    vpR[((size_t)b * N_ + n) * H_ + h] = acc;
    vpT[((size_t)b * H_ + h) * N_ + n] = acc;
  }
}

// ---------------------------------------------------------------------------
// K2: S[b,i,j] = VsSum - 2*sum_h vs[h]/(exp(vp_i+vp_j)+1)  (vp pre-scaled x2)
// SYMMETRIC pre-mask. One (i-tile, j-tile) pair per block, j-tile >= i-tile;
// mirror-writes the transpose. 317 pairs x 8 batches, uniform work.
// ---------------------------------------------------------------------------
__global__ void k_scores(const float* __restrict__ vpR, const float* __restrict__ vpT,
                         const float* __restrict__ vs, const int* __restrict__ mask,
                         float* __restrict__ S) {
  int b = blockIdx.y;
  int bx = blockIdx.x;  // 0..316 -> (it, jt) with jt >= it>>5
  int it, jt;
  if (bx < 128) { it = bx >> 2; jt = bx & 3; }
  else if (bx < 224) { int r = bx - 128; it = 32 + r / 3; jt = 1 + r % 3; }
  else if (bx < 288) { int r = bx - 224; it = 64 + r / 2; jt = 2 + r % 2; }
  else { it = 96 + (bx - 288); jt = 3; }
  int i0 = it * 8;
  int j0 = jt * 256;
  int tid = threadIdx.x;  // 256

  __shared__ float vpi[8][H_];
  __shared__ float vss[H_];
  __shared__ int mki[8];
  __shared__ float vpj[32][256];
  for (int k = 0; k < 4; ++k) {
    int o = k * 256 + tid;  // 1024
    vpi[o >> 7][o & 127] = vpR[((size_t)b * N_ + i0 + (o >> 7)) * H_ + (o & 127)];
  }
  if (tid < H_) vss[tid] = vs[tid];
  if (tid < 8) mki[tid] = mask[(size_t)(i0 + tid) * B_ + b];
  __syncthreads();
  float VsSum = 0.f;
  for (int h = 0; h < H_; ++h) VsSum += vss[h];

  int cnt = min(256, N_ - j0);
  float acc[8] = {0.f, 0.f, 0.f, 0.f, 0.f, 0.f, 0.f, 0.f};
  for (int hc = 0; hc < 4; ++hc) {
    __syncthreads();
    for (int hh = 0; hh < 32; ++hh)
      vpj[hh][tid] = (tid < cnt) ? vpT[((size_t)b * H_ + hc * 32 + hh) * N_ + j0 + tid] : 0.f;
    __syncthreads();
    if (tid < cnt) {
      for (int hh = 0; hh < 32; ++hh) {
        float vj = vpj[hh][tid];
        float vsh = vss[hc * 32 + hh];
#pragma unroll
        for (int i = 0; i < 8; ++i) {
          float e = __expf(vpi[i][hc * 32 + hh] + vj);
          float r = __builtin_amdgcn_rcpf(e + 1.f);
          acc[i] = fmaf(vsh, r, acc[i]);
        }
      }
    }
  }
  int j = j0 + tid;
  if (tid < cnt) {
    float val[8];
#pragma unroll
    for (int i = 0; i < 8; ++i) val[i] = VsSum - 2.f * acc[i];
    if (j >= i0) {
      int mj = mask[(size_t)j * B_ + b];
#pragma unroll
      for (int i = 0; i < 8; ++i)
        S[((size_t)b * N_ + i0 + i) * N_ + j] = mj ? -1e30f : val[i];
    }
    if (j >= i0 + 8) {  // mirror write S[j][i0..i0+7], mask per i
      float4 v0, v1;
      v0.x = mki[0] ? -1e30f : val[0];
      v0.y = mki[1] ? -1e30f : val[1];
      v0.z = mki[2] ? -1e30f : val[2];
      v0.w = mki[3] ? -1e30f : val[3];
      v1.x = mki[4] ? -1e30f : val[4];
      v1.y = mki[5] ? -1e30f : val[5];
      v1.z = mki[6] ? -1e30f : val[6];
      v1.w = mki[7] ? -1e30f : val[7];
      float* row = S + ((size_t)b * N_ + j) * N_ + i0;
      *(float4*)row = v0;
      *(float4*)(row + 4) = v1;
    }
  }
}

// ---------------------------------------------------------------------------
// K3: per-row softmax stats (max, 1/sumexp)
// ---------------------------------------------------------------------------
__global__ void k_rowstats(const float* __restrict__ S, float* __restrict__ m_,
                           float* __restrict__ rl_) {
  int i = blockIdx.x, b = blockIdx.y;
  int lane = threadIdx.x;  // 64
  const float* row = S + ((size_t)b * N_ + i) * N_;
  float mx = -3.0e38f;
  for (int j = lane; j < N_; j += 64) mx = fmaxf(mx, row[j]);
  for (int off = 32; off; off >>= 1) mx = fmaxf(mx, __shfl_xor(mx, off));
  float s = 0.f;
  for (int j = lane; j < N_; j += 64) s += __expf(row[j] - mx);
  for (int off = 32; off; off >>= 1) s += __shfl_xor(s, off);
  if (lane == 0) {
    m_[b * N_ + i] = mx;
    rl_[b * N_ + i] = 1.f / s;
  }
}

// ---------------------------------------------------------------------------
// K4: att[i,b,:] = sum_j P[i,j]*pin[j,b,:]; writes rnn_in = [att | pin]
// grid (8, 63): blockIdx.x = b -> all blocks of one b land on one XCD
// (round-robin dispatch), keeping that b's pin panel L2-resident.
// ---------------------------------------------------------------------------
__global__ void k_pv(const float* __restrict__ S, const float* __restrict__ m_,
                     const float* __restrict__ rl_, const float* __restrict__ pin,
                     float* __restrict__ rnn) {
  int b = blockIdx.x;
  int i0 = blockIdx.y * 16;
  int tid = threadIdx.x;  // 256
  int dg = tid & 63, iq = tid >> 6;
  __shared__ float ps[32][D_];
  __shared__ float PsT[32][16];
  __shared__ float mi[16], ri[16];
  if (tid < 16) {
    int ii = i0 + tid;
    mi[tid] = (ii < N_) ? m_[b * N_ + ii] : 0.f;
    ri[tid] = (ii < N_) ? rl_[b * N_ + ii] : 0.f;
  }
  f32x4 acc[4];
#pragma unroll
  for (int ii = 0; ii < 4; ++ii) acc[ii] = (f32x4){0.f, 0.f, 0.f, 0.f};

  for (int jc = 0; jc < 32; ++jc) {  // 1000 = 31*32 + 8
    int j0 = jc * 32;
    int cj = min(32, N_ - j0);
    __syncthreads();
#pragma unroll
    for (int rr = 0; rr < 8; ++rr) {
      int jj = rr * 4 + iq;
      if (jj < cj)
        *(f32x4*)&ps[jj][dg * 4] =
            *(const f32x4*)&pin[((size_t)(j0 + jj) * B_ + b) * D_ + dg * 4];
    }
#pragma unroll
    for (int k = 0; k < 2; ++k) {
      int v = k * 256 + tid;  // 512 = 32j * 16i
      int jj = v >> 4, il = v & 15;
      float p = 0.f;
      if (jj < cj && i0 + il < N_)
        p = __expf(S[((size_t)b * N_ + i0 + il) * N_ + j0 + jj] - mi[il]) * ri[il];
      PsT[jj][il] = p;
    }
    __syncthreads();
    for (int jj = 0; jj < 32; ++jj) {
      f32x4 pv = *(f32x4*)&ps[jj][dg * 4];
      f32x4 p4 = *(f32x4*)&PsT[jj][iq * 4];
#pragma unroll
      for (int ii = 0; ii < 4; ++ii) acc[ii] += pv * p4[ii];
    }
  }
#pragma unroll
  for (int ii = 0; ii < 4; ++ii) {
    int i = i0 + iq * 4 + ii;
    if (i < N_) {
      size_t base = ((size_t)i * B_ + b) * (2 * D_);
      *(f32x4*)&rnn[base + dg * 4] = acc[ii];
      *(f32x4*)&rnn[base + D_ + dg * 4] =
          *(const f32x4*)&pin[((size_t)i * B_ + b) * D_ + dg * 4];
    }
  }
}

// ---------------------------------------------------------------------------
// K5 v2: xw[n,b,g] = sc(g) * (bias_comb[g] + sum_k rnn[n,b,k]*W_ih[g,k])
// 192 threads, 2 g-rows/thread (gA=tid, gB=tid+192): each wave-uniform LDS
// x-read serves 2 g.
// ---------------------------------------------------------------------------
__global__ void k_xw(const float* __restrict__ rnn, const float* __restrict__ Wf,
                     const float* __restrict__ bf, const float* __restrict__ bhf,
                     const float* __restrict__ Wb, const float* __restrict__ bb,
                     const float* __restrict__ bhb, float* __restrict__ xwf,
                     float* __restrict__ xwb) {
  int n = blockIdx.x;
  int dir = blockIdx.y;
  const float* W = dir ? Wb : Wf;
  const float* bias = dir ? bb : bf;
  const float* bh = dir ? bhb : bhf;
  float* xw = dir ? xwb : xwf;
  int tid = threadIdx.x;  // 192
  __shared__ float xs[B_][2 * D_];
  for (int o = tid; o < B_ * 2 * D_; o += 192)
    ((float*)xs)[o] = rnn[(size_t)n * (B_ * 2 * D_) + o];
  __syncthreads();

  int gA = tid, gB = tid + 192;
  float bvA = bias[gA] + bh[gA];                       // gA < 192 -> always r/z region
  float bvB = bias[gB] + (gB < 256 ? bh[gB] : 0.f);
  float scB = (gB < 256) ? 1.f : 2.f;
  float accA[8], accB[8];
#pragma unroll
  for (int b = 0; b < 8; ++b) { accA[b] = bvA; accB[b] = bvB; }
  const float4* wrA = (const float4*)(W + (size_t)gA * (2 * D_));
  const float4* wrB = (const float4*)(W + (size_t)gB * (2 * D_));
  for (int kq = 0; kq < 128; ++kq) {
    float4 wA = wrA[kq];
    float4 wB = wrB[kq];
#pragma unroll
    for (int b = 0; b < 8; ++b) {
      f32x4 x = *(const f32x4*)&xs[b][kq * 4];
      accA[b] += x[0] * wA.x + x[1] * wA.y + x[2] * wA.z + x[3] * wA.w;
      accB[b] += x[0] * wB.x + x[1] * wB.y + x[2] * wB.z + x[3] * wB.w;
    }
  }
#pragma unroll
  for (int b = 0; b < 8; ++b) {
    xw[((size_t)n * B_ + b) * G3_ + gA] = accA[b];
    xw[((size_t)n * B_ + b) * G3_ + gB] = accB[b] * scB;
  }
}

// ---------------------------------------------------------------------------
// K6: GRU scan v7. 2 blocks (dir) x 512 threads (8 waves, 2/SIMD).
// vs v6: (a) SINGLE-term bf16 W (drop lo residual): MFMA/SIMD/step 48->24,
// halving the ~19.4cyc/MFMA matrix-pipe floor (was the measured bottleneck;
// GRU recurrence is contracting so bf16-W error reaches steady state ~1e-3,
// not a 1000-step accumulation); (b) pointer-marching for xw prefetch and
// out store (constant stride add per use; gate via imm offsets) kills the
// ~60 VALU/step of 64-bit address recomputation.
// ---------------------------------------------------------------------------
__global__ __launch_bounds__(512) void k_gru(const float* __restrict__ xwf,
                                             const float* __restrict__ xwb,
                                             const float* __restrict__ Whf,
                                             const float* __restrict__ Whb,
                                             const float* __restrict__ bhf,
                                             const float* __restrict__ bhb,
                                             float* __restrict__ out) {
  int dir = blockIdx.x;
  const float* xw = dir ? xwb : xwf;
  const float* Wh = dir ? Whb : Whf;
  const float* bh = dir ? bhb : bhf;

  __shared__ short hfh[2][4][64][8];  // buf, kc, slot, j

  int tid = threadIdx.x;
  int w = tid >> 6;     // wave 0..7 -> h-slice [w*16, w*16+16)
  int lane = tid & 63;
  int col = lane & 15;  // b (valid < 8); A row index
  int krow = lane >> 4;

  for (int k = tid; k < 2 * 4 * 64 * 8; k += 512) ((short*)hfh)[k] = 0;

  // W fragments (A operand), gate-scaled: lane holds sc*Wh[g0+col][kc*32+krow*8+j]
  short8_t whi[3][4];
#pragma unroll
  for (int gate = 0; gate < 3; ++gate) {
    float sc = (gate == 2) ? 2.f : 1.f;
    int g0 = gate * 128 + w * 16;
#pragma unroll
    for (int kc = 0; kc < 4; ++kc) {
      const float* wp = Wh + (size_t)(g0 + col) * H_ + kc * 32 + krow * 8;
      short8_t hi8;
#pragma unroll
      for (int j = 0; j < 8; ++j) hi8[j] = (short)f2bf(wp[j] * sc);
      whi[gate][kc] = hi8;
    }
  }
  // n-gate hidden bias (x2); lives inside r*(...) so can't fold into xw
  f32x4 bhn4 = *(const f32x4*)&bh[256 + w * 16 + krow * 4];
  bhn4 *= 2.f;

  f32x4 hprev = {0.f, 0.f, 0.f, 0.f};
  __syncthreads();

  // per-thread invariant offset into an xw step-slab
  int toff = col * G3_ + w * 16 + krow * 4;
  long sstep = dir ? -(long)(4 * B_ * G3_) : (long)(4 * B_ * G3_);  // 4-step slot stride
  // 4 independent prefetch slots; slot s holds xw for steps t == s (mod 4);
  // xp[s] points at the slab for step (current t of slot)+4.
  f32x4 xsq[4][3];
  const float* xp[4];
  if (col < 8) {
#pragma unroll
    for (int s = 0; s < 4; ++s) {
      int ns = dir ? (N_ - 1 - s) : s;
      const float* base = xw + (size_t)ns * (B_ * G3_) + toff;
#pragma unroll
      for (int gate = 0; gate < 3; ++gate)
        xsq[s][gate] = *(const f32x4*)(base + gate * 128);
      xp[s] = base + sstep;  // step s+4
    }
  }
  // out pointer, marched by +-(B*2H) per step
  int n0 = dir ? (N_ - 1) : 0;
  float* outp = out + ((size_t)n0 * B_ + col) * (2 * H_) + dir * H_ + w * 16 + krow * 4;
  long ostep = dir ? -(long)(B_ * 2 * H_) : (long)(B_ * 2 * H_);

#define STEP(T, RBUF, S)                                                       \
  do {                                                                         \
    int t_ = (T);                                                              \
    short8_t fh[4];                                                            \
    _Pragma("unroll") for (int kc = 0; kc < 4; ++kc)                           \
        fh[kc] = *(const short8_t*)&hfh[RBUF][kc][lane][0];                    \
    f32x4 hwv[3];                                                              \
    _Pragma("unroll") for (int gate = 0; gate < 3; ++gate) {                   \
      f32x4 a0 = {0.f, 0.f, 0.f, 0.f};                                         \
      _Pragma("unroll") for (int kc = 0; kc < 4; ++kc)                         \
          a0 = __builtin_amdgcn_mfma_f32_16x16x32_bf16(whi[gate][kc], fh[kc],  \
                                                       a0, 0, 0, 0);           \
      hwv[gate] = a0;                                                          \
    }                                                                          \
    if (col < 8) {                                                             \
      f32x4 h2v;                                                               \
      _Pragma("unroll") for (int i = 0; i < 4; ++i) {                          \
        float er = __expf(xsq[S][0][i] + hwv[0][i]);                           \
        float r = 1.f - __builtin_amdgcn_rcpf(er + 1.f);                       \
        float ez = __expf(xsq[S][1][i] + hwv[1][i]);                           \
        float z = 1.f - __builtin_amdgcn_rcpf(ez + 1.f);                       \
        float en = __expf(fmaf(r, hwv[2][i] + bhn4[i], xsq[S][2][i]));         \
        float nn = fmaf(-2.f, __builtin_amdgcn_rcpf(en + 1.f), 1.f);           \
        float h2 = fmaf(z, hprev[i] - nn, nn);                                 \
        hprev[i] = h2;                                                         \
        h2v[i] = h2;                                                           \
      }                                                                        \
      int c0 = w * 16 + krow * 4;                                              \
      int kc_ = c0 >> 5, slot_ = ((c0 >> 3) & 3) * 16 + col, j0_ = c0 & 7;     \
      short4_t hi4;                                                            \
      _Pragma("unroll") for (int i = 0; i < 4; ++i)                            \
          hi4[i] = (short)f2bf(h2v[i]);                                        \
      *(short4_t*)&hfh[(RBUF) ^ 1][kc_][slot_][j0_] = hi4;                     \
      *(f32x4*)outp = h2v;                                                     \
      outp += ostep;                                                           \
      _Pragma("unroll") for (int gate = 0; gate < 3; ++gate)                   \
          xsq[S][gate] = *(const f32x4*)(xp[S] + gate * 128);                  \
      const float* xpn_ = xp[S] + sstep;                                       \
      xp[S] = (t_ + 8 < N_) ? xpn_ : xp[S];                                    \
    }                                                                          \
    asm volatile("s_waitcnt lgkmcnt(0)\n\ts_barrier" ::: "memory");            \
  } while (0)

  for (int t4 = 0; t4 < N_; t4 += 4) {
    STEP(t4 + 0, 0, 0);
    STEP(t4 + 1, 1, 1);
    STEP(t4 + 2, 0, 2);
    STEP(t4 + 3, 1, 3);
  }
#undef STEP
}

// ---------------------------------------------------------------------------
extern "C" void kernel_launch(void* const* d_in, const int* in_sizes, int n_in,
                              void* d_out, int out_size, void* d_ws, size_t ws_size,
                              hipStream_t stream) {
  const float* pin  = (const float*)d_in[0];
  const int*   mask = (const int*)d_in[1];
  const float* W0   = (const float*)d_in[2];
  const float* vs   = (const float*)d_in[3];
  const float* Wihf = (const float*)d_in[4];
  const float* Whhf = (const float*)d_in[5];
  const float* bihf = (const float*)d_in[6];
  const float* bhhf = (const float*)d_in[7];
  const float* Wihb = (const float*)d_in[8];
  const float* Whhb = (const float*)d_in[9];
  const float* bihb = (const float*)d_in[10];
  const float* bhhb = (const float*)d_in[11];
  float* out = (float*)d_out;
  float* ws = (float*)d_ws;

  float* vpR = ws;                  // 1,024,000
  float* vpT = ws + 1024000;        // 1,024,000
  float* S   = ws + 2048000;        // 8,000,000
  float* m_  = ws + 10048000;       // 8,000
  float* rl_ = ws + 10056000;       // 8,000
  float* rnn = ws + 10064000;       // 4,096,000
  float* xwf = ws + 14160000;       // 3,072,000
  float* xwb = ws + 17232000;       // 3,072,000

  hipLaunchKernelGGL(k_vp, dim3(N_), dim3(256), 0, stream, pin, W0, vpR, vpT);
  hipLaunchKernelGGL(k_scores, dim3(317, 8), dim3(256), 0, stream, vpR, vpT, vs, mask, S);
  hipLaunchKernelGGL(k_rowstats, dim3(N_, 8), dim3(64), 0, stream, S, m_, rl_);
  hipLaunchKernelGGL(k_pv, dim3(8, 63), dim3(256), 0, stream, S, m_, rl_, pin, rnn);
  hipLaunchKernelGGL(k_xw, dim3(N_, 2), dim3(192), 0, stream, rnn, Wihf, bihf, bhhf,
                     Wihb, bihb, bhhb, xwf, xwb);
  hipLaunchKernelGGL(k_gru, dim3(2), dim3(512), 0, stream, xwf, xwb, Whhf, Whhb,
                     bhhf, bhhb, out);
}

// Round 10
// 1224.134 us; speedup vs baseline: 2.1743x; 1.0940x over previous
//
#include <hip/hip_runtime.h>

// ---------------------------------------------------------------------------
// SelfMatchEncoder: additive self-attention + bidirectional GRU
// N=1000, B=8, D=256, H=128
// ---------------------------------------------------------------------------

#define N_ 1000
#define B_ 8
#define D_ 256
#define H_ 128
#define G3_ 384  // 3*H

typedef __attribute__((ext_vector_type(4))) float f32x4;

// ---------------------------------------------------------------------------
// K1: vp[n,b,h] = 2 * sum_d pin[n,b,d]*W0[h,d]   (x2 folded for tanh-via-exp)
// ---------------------------------------------------------------------------
__global__ void k_vp(const float* __restrict__ pin, const float* __restrict__ W0,
                     float* __restrict__ vpR, float* __restrict__ vpT) {
  int n = blockIdx.x;
  int tid = threadIdx.x;  // 256
  __shared__ float xs[B_][D_];
  for (int k = 0; k < 8; ++k) {
    int idx = k * 256 + tid;  // 2048
    xs[idx >> 8][idx & 255] = pin[(size_t)n * (B_ * D_) + idx];
  }
  __syncthreads();
  for (int k = 0; k < 4; ++k) {
    int o = k * 256 + tid;  // 1024 = 8b * 128h
    int b = o >> 7, h = o & 127;
    const float4* wr = (const float4*)(W0 + (size_t)h * D_);
    float acc = 0.f;
#pragma unroll 8
    for (int dq = 0; dq < 64; ++dq) {
      float4 w = wr[dq];
      acc += xs[b][dq * 4 + 0] * w.x + xs[b][dq * 4 + 1] * w.y +
             xs[b][dq * 4 + 2] * w.z + xs[b][dq * 4 + 3] * w.w;
    }
    acc *= 2.f;
    vpR[((size_t)b * N_ + n) * H_ + h] = acc;
    vpT[((size_t)b * H_ + h) * N_ + n] = acc;
  }
}

// ---------------------------------------------------------------------------
// K2: S[b,i,j] = VsSum - 2*sum_h vs[h]/(exp(vp_i+vp_j)+1)  (vp pre-scaled x2)
// SYMMETRIC pre-mask; j-tile >= i-tile with mirror write. Inner loop unrolled
// x4 with b128 vpi/vss reads: LDS instrs 36 -> 13 per 4-hh group.
// ---------------------------------------------------------------------------
__global__ void k_scores(const float* __restrict__ vpR, const float* __restrict__ vpT,
                         const float* __restrict__ vs, const int* __restrict__ mask,
                         float* __restrict__ S) {
  int b = blockIdx.y;
  int bx = blockIdx.x;  // 0..316 -> (it, jt) with jt >= it>>5
  int it, jt;
  if (bx < 128) { it = bx >> 2; jt = bx & 3; }
  else if (bx < 224) { int r = bx - 128; it = 32 + r / 3; jt = 1 + r % 3; }
  else if (bx < 288) { int r = bx - 224; it = 64 + r / 2; jt = 2 + r % 2; }
  else { it = 96 + (bx - 288); jt = 3; }
  int i0 = it * 8;
  int j0 = jt * 256;
  int tid = threadIdx.x;  // 256

  __shared__ float vpi[8][H_];
  __shared__ float vss[H_];
  __shared__ int mki[8];
  __shared__ float vpj[32][256];
  for (int k = 0; k < 4; ++k) {
    int o = k * 256 + tid;  // 1024
    vpi[o >> 7][o & 127] = vpR[((size_t)b * N_ + i0 + (o >> 7)) * H_ + (o & 127)];
  }
  if (tid < H_) vss[tid] = vs[tid];
  if (tid < 8) mki[tid] = mask[(size_t)(i0 + tid) * B_ + b];
  __syncthreads();
  float VsSum = 0.f;
  for (int h = 0; h < H_; ++h) VsSum += vss[h];

  int cnt = min(256, N_ - j0);
  float acc[8] = {0.f, 0.f, 0.f, 0.f, 0.f, 0.f, 0.f, 0.f};
  for (int hc = 0; hc < 4; ++hc) {
    __syncthreads();
    for (int hh = 0; hh < 32; ++hh)
      vpj[hh][tid] = (tid < cnt) ? vpT[((size_t)b * H_ + hc * 32 + hh) * N_ + j0 + tid] : 0.f;
    __syncthreads();
    if (tid < cnt) {
      for (int h4 = 0; h4 < 8; ++h4) {
        f32x4 vs4 = *(const f32x4*)&vss[hc * 32 + h4 * 4];
        f32x4 vi[8];
#pragma unroll
        for (int i = 0; i < 8; ++i) vi[i] = *(const f32x4*)&vpi[i][hc * 32 + h4 * 4];
#pragma unroll
        for (int u = 0; u < 4; ++u) {
          float vj = vpj[h4 * 4 + u][tid];
#pragma unroll
          for (int i = 0; i < 8; ++i) {
            float e = __expf(vi[i][u] + vj);
            acc[i] = fmaf(vs4[u], __builtin_amdgcn_rcpf(e + 1.f), acc[i]);
          }
        }
      }
    }
  }
  int j = j0 + tid;
  if (tid < cnt) {
    float val[8];
#pragma unroll
    for (int i = 0; i < 8; ++i) val[i] = VsSum - 2.f * acc[i];
    if (j >= i0) {
      int mj = mask[(size_t)j * B_ + b];
#pragma unroll
      for (int i = 0; i < 8; ++i)
        S[((size_t)b * N_ + i0 + i) * N_ + j] = mj ? -1e30f : val[i];
    }
    if (j >= i0 + 8) {  // mirror write S[j][i0..i0+7], mask per i
      float4 v0, v1;
      v0.x = mki[0] ? -1e30f : val[0];
      v0.y = mki[1] ? -1e30f : val[1];
      v0.z = mki[2] ? -1e30f : val[2];
      v0.w = mki[3] ? -1e30f : val[3];
      v1.x = mki[4] ? -1e30f : val[4];
      v1.y = mki[5] ? -1e30f : val[5];
      v1.z = mki[6] ? -1e30f : val[6];
      v1.w = mki[7] ? -1e30f : val[7];
      float* row = S + ((size_t)b * N_ + j) * N_ + i0;
      *(float4*)row = v0;
      *(float4*)(row + 4) = v1;
    }
  }
}

// ---------------------------------------------------------------------------
// K3: per-row softmax stats (max, 1/sumexp)
// ---------------------------------------------------------------------------
__global__ void k_rowstats(const float* __restrict__ S, float* __restrict__ m_,
                           float* __restrict__ rl_) {
  int i = blockIdx.x, b = blockIdx.y;
  int lane = threadIdx.x;  // 64
  const float* row = S + ((size_t)b * N_ + i) * N_;
  float mx = -3.0e38f;
  for (int j = lane; j < N_; j += 64) mx = fmaxf(mx, row[j]);
  for (int off = 32; off; off >>= 1) mx = fmaxf(mx, __shfl_xor(mx, off));
  float s = 0.f;
  for (int j = lane; j < N_; j += 64) s += __expf(row[j] - mx);
  for (int off = 32; off; off >>= 1) s += __shfl_xor(s, off);
  if (lane == 0) {
    m_[b * N_ + i] = mx;
    rl_[b * N_ + i] = 1.f / s;
  }
}

// ---------------------------------------------------------------------------
// K4: att[i,b,:] = sum_j P[i,j]*pin[j,b,:]; writes rnn_in = [att | pin]
// grid (8, 63): blockIdx.x = b keeps each b's pin panel on one XCD's L2.
// ---------------------------------------------------------------------------
__global__ void k_pv(const float* __restrict__ S, const float* __restrict__ m_,
                     const float* __restrict__ rl_, const float* __restrict__ pin,
                     float* __restrict__ rnn) {
  int b = blockIdx.x;
  int i0 = blockIdx.y * 16;
  int tid = threadIdx.x;  // 256
  int dg = tid & 63, iq = tid >> 6;
  __shared__ float ps[32][D_];
  __shared__ float PsT[32][16];
  __shared__ float mi[16], ri[16];
  if (tid < 16) {
    int ii = i0 + tid;
    mi[tid] = (ii < N_) ? m_[b * N_ + ii] : 0.f;
    ri[tid] = (ii < N_) ? rl_[b * N_ + ii] : 0.f;
  }
  f32x4 acc[4];
#pragma unroll
  for (int ii = 0; ii < 4; ++ii) acc[ii] = (f32x4){0.f, 0.f, 0.f, 0.f};

  for (int jc = 0; jc < 32; ++jc) {  // 1000 = 31*32 + 8
    int j0 = jc * 32;
    int cj = min(32, N_ - j0);
    __syncthreads();
#pragma unroll
    for (int rr = 0; rr < 8; ++rr) {
      int jj = rr * 4 + iq;
      if (jj < cj)
        *(f32x4*)&ps[jj][dg * 4] =
            *(const f32x4*)&pin[((size_t)(j0 + jj) * B_ + b) * D_ + dg * 4];
    }
#pragma unroll
    for (int k = 0; k < 2; ++k) {
      int v = k * 256 + tid;  // 512 = 32j * 16i
      int jj = v >> 4, il = v & 15;
      float p = 0.f;
      if (jj < cj && i0 + il < N_)
        p = __expf(S[((size_t)b * N_ + i0 + il) * N_ + j0 + jj] - mi[il]) * ri[il];
      PsT[jj][il] = p;
    }
    __syncthreads();
    for (int jj = 0; jj < 32; ++jj) {
      f32x4 pv = *(f32x4*)&ps[jj][dg * 4];
      f32x4 p4 = *(f32x4*)&PsT[jj][iq * 4];
#pragma unroll
      for (int ii = 0; ii < 4; ++ii) acc[ii] += pv * p4[ii];
    }
  }
#pragma unroll
  for (int ii = 0; ii < 4; ++ii) {
    int i = i0 + iq * 4 + ii;
    if (i < N_) {
      size_t base = ((size_t)i * B_ + b) * (2 * D_);
      *(f32x4*)&rnn[base + dg * 4] = acc[ii];
      *(f32x4*)&rnn[base + D_ + dg * 4] =
          *(const f32x4*)&pin[((size_t)i * B_ + b) * D_ + dg * 4];
    }
  }
}

// ---------------------------------------------------------------------------
// K5 v2: xw[n,b,g] = sc(g) * (bias_comb[g] + sum_k rnn[n,b,k]*W_ih[g,k])
// bias_comb = b_ih + b_hh for r,z; sc = 1 (r,z) / 2 (n) for exp-based gates.
// ---------------------------------------------------------------------------
__global__ void k_xw(const float* __restrict__ rnn, const float* __restrict__ Wf,
                     const float* __restrict__ bf, const float* __restrict__ bhf,
                     const float* __restrict__ Wb, const float* __restrict__ bb,
                     const float* __restrict__ bhb, float* __restrict__ xwf,
                     float* __restrict__ xwb) {
  int n = blockIdx.x;
  int dir = blockIdx.y;
  const float* W = dir ? Wb : Wf;
  const float* bias = dir ? bb : bf;
  const float* bh = dir ? bhb : bhf;
  float* xw = dir ? xwb : xwf;
  int tid = threadIdx.x;  // 192
  __shared__ float xs[B_][2 * D_];
  for (int o = tid; o < B_ * 2 * D_; o += 192)
    ((float*)xs)[o] = rnn[(size_t)n * (B_ * 2 * D_) + o];
  __syncthreads();

  int gA = tid, gB = tid + 192;
  float bvA = bias[gA] + bh[gA];  // gA < 192 -> always r/z region
  float bvB = bias[gB] + (gB < 256 ? bh[gB] : 0.f);
  float scB = (gB < 256) ? 1.f : 2.f;
  float accA[8], accB[8];
#pragma unroll
  for (int b = 0; b < 8; ++b) { accA[b] = bvA; accB[b] = bvB; }
  const float4* wrA = (const float4*)(W + (size_t)gA * (2 * D_));
  const float4* wrB = (const float4*)(W + (size_t)gB * (2 * D_));
  for (int kq = 0; kq < 128; ++kq) {
    float4 wA = wrA[kq];
    float4 wB = wrB[kq];
#pragma unroll
    for (int b = 0; b < 8; ++b) {
      f32x4 x = *(const f32x4*)&xs[b][kq * 4];
      accA[b] += x[0] * wA.x + x[1] * wA.y + x[2] * wA.z + x[3] * wA.w;
      accB[b] += x[0] * wB.x + x[1] * wB.y + x[2] * wB.z + x[3] * wB.w;
    }
  }
#pragma unroll
  for (int b = 0; b < 8; ++b) {
    xw[((size_t)n * B_ + b) * G3_ + gA] = accA[b];
    xw[((size_t)n * B_ + b) * G3_ + gB] = accB[b] * scB;
  }
}

// ---------------------------------------------------------------------------
// K6: GRU scan v8. 16 blocks (dir x batch) x 512 threads (8 waves, 2/SIMD).
// Pure fp32 VALU (no MFMA, no bf16): per block 384g x 128k x 1b = 49K MAC
// per step = 384 FMA-cycles/CU (< the 466-cyc MFMA floor, no col waste, no
// rounding). Thread (gg=tid>>2, kq=tid&3): output c=gg, k-quarter kq; W rows
// r/z/n in 96 VGPRs; h in padded LDS (conflict-free b128 broadcast);
// butterfly shfl over 4 kq lanes; gates in all lanes (no exec waste);
// kq==0 writes h2. 4-slot pointer-marched xw prefetch + LDS-only barrier.
// ---------------------------------------------------------------------------
__global__ __launch_bounds__(512) void k_gru(const float* __restrict__ xwf,
                                             const float* __restrict__ xwb,
                                             const float* __restrict__ Whf,
                                             const float* __restrict__ Whb,
                                             const float* __restrict__ bhf,
                                             const float* __restrict__ bhb,
                                             float* __restrict__ out) {
  int bid = blockIdx.x;  // 0..15
  int dir = bid >> 3;
  int b = bid & 7;
  const float* xw = dir ? xwb : xwf;
  const float* Wh = dir ? Whb : Whf;
  const float* bh = dir ? bhb : bhf;

  __shared__ float hsh[2][4 * 36];  // double buffer; k-quarter regions padded to 36

  int tid = threadIdx.x;
  int gg = tid >> 2;  // output c = gg (0..127)
  int kq = tid & 3;   // k quarter

  for (int k = tid; k < 2 * 4 * 36; k += 512) ((float*)hsh)[k] = 0.f;

  // W rows (fp32), n-gate pre-scaled x2
  float wr[32], wz[32], wn[32];
  {
    const float* wpr = Wh + (size_t)gg * H_ + kq * 32;
    const float* wpz = Wh + (size_t)(128 + gg) * H_ + kq * 32;
    const float* wpn = Wh + (size_t)(256 + gg) * H_ + kq * 32;
#pragma unroll
    for (int j = 0; j < 32; j += 4) {
      *(f32x4*)&wr[j] = *(const f32x4*)&wpr[j];
      *(f32x4*)&wz[j] = *(const f32x4*)&wpz[j];
      f32x4 t = *(const f32x4*)&wpn[j];
      t *= 2.f;
      *(f32x4*)&wn[j] = t;
    }
  }
  float bhn2 = 2.f * bh[256 + gg];
  float hprev = 0.f;
  __syncthreads();

  // 4-slot xw prefetch, pointer-marched
  long sstep = dir ? -(long)(4 * B_ * G3_) : (long)(4 * B_ * G3_);
  float xr_[4], xz_[4], xn_[4];
  const float* xp[4];
#pragma unroll
  for (int s = 0; s < 4; ++s) {
    int ns = dir ? (N_ - 1 - s) : s;
    const float* base = xw + (size_t)ns * (B_ * G3_) + b * G3_ + gg;
    xr_[s] = base[0];
    xz_[s] = base[128];
    xn_[s] = base[256];
    xp[s] = base + sstep;
  }
  int n0 = dir ? (N_ - 1) : 0;
  float* outp = out + ((size_t)n0 * B_ + b) * (2 * H_) + dir * H_ + gg;
  long ostep = dir ? -(long)(B_ * 2 * H_) : (long)(B_ * 2 * H_);

#define STEP(T, RBUF, S)                                                       \
  do {                                                                         \
    const float* hb = &hsh[RBUF][kq * 36];                                     \
    float ar = 0.f, az = 0.f, an = 0.f, ar2 = 0.f, az2 = 0.f, an2 = 0.f;       \
    _Pragma("unroll") for (int j = 0; j < 32; j += 8) {                        \
      f32x4 h0 = *(const f32x4*)&hb[j];                                        \
      f32x4 h1 = *(const f32x4*)&hb[j + 4];                                    \
      _Pragma("unroll") for (int u = 0; u < 4; ++u) {                          \
        ar = fmaf(wr[j + u], h0[u], ar);                                       \
        az = fmaf(wz[j + u], h0[u], az);                                       \
        an = fmaf(wn[j + u], h0[u], an);                                       \
        ar2 = fmaf(wr[j + 4 + u], h1[u], ar2);                                 \
        az2 = fmaf(wz[j + 4 + u], h1[u], az2);                                 \
        an2 = fmaf(wn[j + 4 + u], h1[u], an2);                                 \
      }                                                                        \
    }                                                                          \
    ar += ar2; az += az2; an += an2;                                           \
    ar += __shfl_xor(ar, 1); ar += __shfl_xor(ar, 2);                          \
    az += __shfl_xor(az, 1); az += __shfl_xor(az, 2);                          \
    an += __shfl_xor(an, 1); an += __shfl_xor(an, 2);                          \
    float er = __expf(xr_[S] + ar);                                            \
    float r = 1.f - __builtin_amdgcn_rcpf(er + 1.f);                           \
    float ez = __expf(xz_[S] + az);                                            \
    float z = 1.f - __builtin_amdgcn_rcpf(ez + 1.f);                           \
    float en = __expf(fmaf(r, an + bhn2, xn_[S]));                             \
    float nn = fmaf(-2.f, __builtin_amdgcn_rcpf(en + 1.f), 1.f);               \
    float h2 = fmaf(z, hprev - nn, nn);                                        \
    hprev = h2;                                                                \
    if (kq == 0) {                                                             \
      hsh[(RBUF) ^ 1][(gg >> 5) * 36 + (gg & 31)] = h2;                        \
      *outp = h2;                                                              \
    }                                                                          \
    outp += ostep;                                                             \
    xr_[S] = xp[S][0];                                                         \
    xz_[S] = xp[S][128];                                                       \
    xn_[S] = xp[S][256];                                                       \
    const float* xpn_ = xp[S] + sstep;                                         \
    xp[S] = ((T) + 8 < N_) ? xpn_ : xp[S];                                     \
    asm volatile("s_waitcnt lgkmcnt(0)\n\ts_barrier" ::: "memory");            \
  } while (0)

  for (int t4 = 0; t4 < N_; t4 += 4) {
    STEP(t4 + 0, 0, 0);
    STEP(t4 + 1, 1, 1);
    STEP(t4 + 2, 0, 2);
    STEP(t4 + 3, 1, 3);
  }
#undef STEP
}

// ---------------------------------------------------------------------------
extern "C" void kernel_launch(void* const* d_in, const int* in_sizes, int n_in,
                              void* d_out, int out_size, void* d_ws, size_t ws_size,
                              hipStream_t stream) {
  const float* pin  = (const float*)d_in[0];
  const int*   mask = (const int*)d_in[1];
  const float* W0   = (const float*)d_in[2];
  const float* vs   = (const float*)d_in[3];
  const float* Wihf = (const float*)d_in[4];
  const float* Whhf = (const float*)d_in[5];
  const float* bihf = (const float*)d_in[6];
  const float* bhhf = (const float*)d_in[7];
  const float* Wihb = (const float*)d_in[8];
  const float* Whhb = (const float*)d_in[9];
  const float* bihb = (const float*)d_in[10];
  const float* bhhb = (const float*)d_in[11];
  float* out = (float*)d_out;
  float* ws = (float*)d_ws;

  float* vpR = ws;                  // 1,024,000
  float* vpT = ws + 1024000;        // 1,024,000
  float* S   = ws + 2048000;        // 8,000,000
  float* m_  = ws + 10048000;       // 8,000
  float* rl_ = ws + 10056000;       // 8,000
  float* rnn = ws + 10064000;       // 4,096,000
  float* xwf = ws + 14160000;       // 3,072,000
  float* xwb = ws + 17232000;       // 3,072,000

  hipLaunchKernelGGL(k_vp, dim3(N_), dim3(256), 0, stream, pin, W0, vpR, vpT);
  hipLaunchKernelGGL(k_scores, dim3(317, 8), dim3(256), 0, stream, vpR, vpT, vs, mask, S);
  hipLaunchKernelGGL(k_rowstats, dim3(N_, 8), dim3(64), 0, stream, S, m_, rl_);
  hipLaunchKernelGGL(k_pv, dim3(8, 63), dim3(256), 0, stream, S, m_, rl_, pin, rnn);
  hipLaunchKernelGGL(k_xw, dim3(N_, 2), dim3(192), 0, stream, rnn, Wihf, bihf, bhhf,
                     Wihb, bihb, bhhb, xwf, xwb);
  hipLaunchKernelGGL(k_gru, dim3(16), dim3(512), 0, stream, xwf, xwb, Whhf, Whhb,
                     bhhf, bhhb, out);
}